// Round 8
// baseline (406.904 us; speedup 1.0000x reference)
//
#include <hip/hip_runtime.h>

#define HDIM 256
#define CAPN 4096
#define CAPE (CAPN * 8)
#define NB 128
#define NT 256

// meta: [0]=shared slot counter, [5+k]=edge count layer k (k=0..2), [8]=int32 flag.
// map[u]: 0=absent, 1=claim-in-progress, else ((slot+1)<<2)|birth, birth in {0..3}.
// Node u in S_l  <=>  map[u]>=4 && (map[u]&3) >= l  (sets nested S3<=S2<=S1<=S0).

// Device-scope grid barrier: one monotonic slot per barrier, zeroed by host memset.
// 128 blocks on 256 CUs are always co-resident -> no deadlock.
__device__ __forceinline__ void gbar(int* slot) {
  __syncthreads();
  if (threadIdx.x == 0) {
    __threadfence();  // release: prior writes device-visible
    __hip_atomic_fetch_add(slot, 1, __ATOMIC_RELEASE, __HIP_MEMORY_SCOPE_AGENT);
    while (__hip_atomic_load(slot, __ATOMIC_ACQUIRE, __HIP_MEMORY_SCOPE_AGENT) < NB)
      __builtin_amdgcn_s_sleep(2);
    __threadfence();  // acquire: invalidate stale caches before reads
  }
  __syncthreads();
}

__global__ void __launch_bounds__(NT, 1) k_mega(
    const float* __restrict__ x, const int* __restrict__ ei,
    const float* __restrict__ ea, const int* __restrict__ tgt,
    const float* __restrict__ Wi, const float* __restrict__ bi,
    const float* __restrict__ Wg, const float* __restrict__ bg,
    const float* __restrict__ Wo1, const float* __restrict__ bo1,
    const float* __restrict__ Wo2, const float* __restrict__ bo2,
    const float* __restrict__ Wh1, const float* __restrict__ bh1,
    const float* __restrict__ Wh2, const float* __restrict__ bh2,
    const float* __restrict__ Wh3, const float* __restrict__ bh3,
    int N, int E, int* __restrict__ map, int* __restrict__ meta,
    float* __restrict__ deg, int* __restrict__ nodeof,
    int* __restrict__ el0, int* __restrict__ el1, int* __restrict__ el2,
    float* __restrict__ g, float* __restrict__ hA, float* __restrict__ hB,
    float* __restrict__ headv, int* __restrict__ bar, float* __restrict__ out) {
  __shared__ float sh[1024];
  const int tid = threadIdx.x, bid = blockIdx.x;
  const int gtid = bid * NT + tid, gsz = NB * NT;

  // ---- phase 0: zero map/deg, init meta, detect int64/int32, seed target ----
  {
    int t = tgt[0];
    for (int i = gtid; i < N; i += gsz) map[i] = (i == t) ? 7 : 0;  // target: slot0,birth3
    for (int i = gtid; i < CAPN; i += gsz) deg[i] = 0.0f;
    if (bid == 0 && tid < 64) {
      bool nz = (tid < E) && (ei[2 * tid + 1] != 0);
      unsigned long long b = __ballot(nz);
      if (tid == 0) {
        meta[8] = (b != 0ULL) ? 1 : 0;
        meta[0] = 1; meta[5] = 0; meta[6] = 0; meta[7] = 0;
        nodeof[0] = t;
      }
    }
  }
  gbar(&bar[0]);

  const int st = meta[8] ? 1 : 2;

  // ---- phases 1-3: frontier expansion l=3,2,1 (proven round-7 body) ----
  for (int l = 3; l >= 1; --l) {
    int* elist = (l == 3) ? el2 : (l == 2) ? el1 : el0;
    int ecntIdx = 5 + (l - 1);
    for (int e = gtid; e < E; e += gsz) {
      int c = ei[(size_t)(E + e) * st];
      int mv = map[c];
      if (mv >= 4 && (mv & 3) >= l) {   // mid-phase claims have birth l-1: excluded
        int r = ei[(size_t)e * st];
        int s = atomicAdd(&meta[ecntIdx], 1);
        if (s < CAPE) elist[s] = e;
        if (atomicCAS(&map[r], 0, 1) == 0) {
          int ns = atomicAdd(&meta[0], 1);
          if (ns < CAPN) { nodeof[ns] = r; map[r] = ((ns + 1) << 2) | (l - 1); }
        }
      }
    }
    gbar(&bar[4 - l]);  // slots 1,2,3
  }

  int ntot = meta[0]; if (ntot > CAPN) ntot = CAPN;

  // ---- phase 4: compact in-degree (blocks 0..63) || h0 projection (64..127) ----
  if (bid < 64) {
    int t2 = bid * NT + tid, tot2 = 64 * NT;
    for (int e = t2; e < E; e += tot2) {
      int c = ei[(size_t)(E + e) * st];
      int mv = map[c];
      if (mv >= 4) atomicAdd(&deg[(mv >> 2) - 1], ea[e]);
    }
  } else {
    float* xs = sh;
    for (int s = bid - 64; s < ntot; s += 64) {
      int u = nodeof[s];
      if (tid < 100) xs[tid] = x[(size_t)u * 100 + tid];
      __syncthreads();
      float acc = bi[tid];
#pragma unroll 4
      for (int k = 0; k < 100; ++k) acc = fmaf(xs[k], Wi[k * HDIM + tid], acc);
      hA[(size_t)s * HDIM + tid] = fmaxf(acc, 0.0f);
      __syncthreads();
    }
  }
  gbar(&bar[4]);

  // ---- phases 5-10: 3 GCN layers (gemv+self | scatter), proven bodies ----
  float* hin = hA;
  float* hout = hB;
  for (int k = 0; k < 3; ++k) {
    const float* W  = Wg + (size_t)k * HDIM * HDIM;
    const float* bk = bg + (size_t)k * HDIM;
    float* hs = sh;
    for (int s = bid; s < ntot; s += NB) {
      float hv = hin[(size_t)s * HDIM + tid];
      hs[tid] = (k == 0) ? hv : fmaxf(hv, 0.0f);
      __syncthreads();
      float acc = 0.0f;
#pragma unroll 8
      for (int m = 0; m < HDIM; ++m) acc = fmaf(hs[m], W[m * HDIM + tid], acc);
      g[(size_t)s * HDIM + tid] = acc;
      int mv = map[nodeof[s]];
      if ((mv & 3) >= k + 1) {          // s in S_{k+1}: bias + self-loop message
        float dv = 1.0f / sqrtf(deg[s] + 1.0f);
        hout[(size_t)s * HDIM + tid] = bk[tid] + dv * dv * acc;
      }
      __syncthreads();
    }
    gbar(&bar[5 + 2 * k]);

    int ne = meta[5 + k]; if (ne > CAPE) ne = CAPE;
    const int* elist = (k == 0) ? el0 : (k == 1) ? el1 : el2;
    for (int i = bid; i < ne; i += NB) {
      int e = elist[i];
      int u = ei[(size_t)e * st];
      int v = ei[(size_t)(E + e) * st];
      int mu = map[u], mv = map[v];
      if (mu < 4 || mv < 4) continue;   // overflow guard (flagged at tail)
      int su = (mu >> 2) - 1, sv = (mv >> 2) - 1;
      float du  = 1.0f / sqrtf(deg[su] + 1.0f);
      float dvv = 1.0f / sqrtf(deg[sv] + 1.0f);
      float nrm = du * ea[e] * dvv;
      atomicAdd(&hout[(size_t)sv * HDIM + tid], nrm * g[(size_t)su * HDIM + tid]);
    }
    gbar(&bar[6 + 2 * k]);
    float* tmp = hin; hin = hout; hout = tmp;
  }
  // hin row 0 = target's h3 (slot 0 seeded at birth)

  // ---- phase 11: head stage1 (redundant per block, LDS) + stage2 (64 outs/block) ----
  float* v2 = headv;  // 512 floats, global
  if (bid < 8) {
    float* vs  = sh;        // 256: h3 row 0
    float* v1s = sh + 256;  // 512: relu(h3 @ Wo1 + bo1), computed fully per block
    float* red = sh + 768;  // 256
    vs[tid] = hin[tid];
    __syncthreads();
    for (int j = tid; j < 512; j += NT) {
      float a = bo1[j];
#pragma unroll 4
      for (int k = 0; k < 256; ++k) a = fmaf(vs[k], Wo1[(size_t)k * 512 + j], a);
      v1s[j] = fmaxf(a, 0.0f);
    }
    __syncthreads();
    int tx = tid & 63, ty = tid >> 6;
    int j = bid * 64 + tx;
    float acc = 0.0f;
#pragma unroll 4
    for (int k = ty * 128; k < ty * 128 + 128; ++k)
      acc = fmaf(v1s[k], Wo2[(size_t)k * 512 + j], acc);
    red[ty * 64 + tx] = acc;
    __syncthreads();
    if (ty == 0)
      v2[j] = red[tx] + red[64 + tx] + red[128 + tx] + red[192 + tx] + bo2[j];
  }
  gbar(&bar[11]);

  // ---- phase 12: tail in block 0: v3=relu(v2@Wh1+bh1), v4=relu(v3@Wh2+bh2), out ----
  if (bid == 0) {
    float* v2s  = sh;        // 512
    float* v3s  = sh + 512;  // 256
    float* part = sh + 768;  // 256
    v2s[tid] = v2[tid];
    v2s[tid + 256] = v2[tid + 256];
    __syncthreads();
    float a3 = bh1[tid];
#pragma unroll 4
    for (int k = 0; k < 512; ++k) a3 = fmaf(v2s[k], Wh1[(size_t)k * 256 + tid], a3);
    v3s[tid] = fmaxf(a3, 0.0f);
    __syncthreads();
    int o = tid & 127, half = tid >> 7;
    float acc = 0.0f;
#pragma unroll 4
    for (int k = half * 128; k < half * 128 + 128; ++k)
      acc = fmaf(v3s[k], Wh2[(size_t)k * 128 + o], acc);
    part[tid] = acc;
    __syncthreads();
    float* v4 = sh;  // reuse v2s region (consumed)
    if (tid < 128) v4[tid] = fmaxf(part[tid] + part[tid + 128] + bh2[tid], 0.0f);
    __syncthreads();
    if (tid < 5) {
      float a = bh3[tid];
#pragma unroll 4
      for (int k = 0; k < 128; ++k) a = fmaf(v4[k], Wh3[k * 5 + tid], a);
      if (tid == 4) {
        int B = 0;
        if (meta[0] > CAPN) B |= 1;
        if (meta[5] > CAPE || meta[6] > CAPE || meta[7] > CAPE) B |= 2;
        if (B) a = 1.0e6f * (float)B;
      }
      out[tid] = a;
    }
  }
}

// Diagnostic: out = [0,0,0,0,D]
__global__ void k_diag(float* __restrict__ out, float D) {
  int tid = threadIdx.x;
  if (tid < 4) out[tid] = 0.0f;
  if (tid == 4) out[tid] = D;
}

extern "C" void kernel_launch(void* const* d_in, const int* in_sizes, int n_in,
                              void* d_out, int out_size, void* d_ws, size_t ws_size,
                              hipStream_t stream) {
  float* out = (float*)d_out;

  // ---- input-mapping tripwire (proven good) ----
  static const long long EXP[18] = {5000000, 600000, 300000, 1, 25600, 256, 196608, 768,
                                    131072, 512, 262144, 512, 131072, 256, 32768, 128, 640, 5};
  if (n_in != 18) {
    k_diag<<<1, 64, 0, stream>>>(out, 3.0e6f + 1000.0f * (float)n_in);
    return;
  }
  for (int i = 0; i < 18; ++i) {
    long long s = in_sizes[i];
    bool ok = (s == EXP[i]) || (i == 1 && s == 2 * EXP[1]);
    if (!ok) {
      k_diag<<<1, 64, 0, stream>>>(out, (float)(i + 1) * 1.0e5f);
      return;
    }
  }

  const float* x   = (const float*)d_in[0];
  const int*   ei  = (const int*)d_in[1];
  const float* ea  = (const float*)d_in[2];
  const int*   tgt = (const int*)d_in[3];
  const float* Wi  = (const float*)d_in[4];
  const float* bi  = (const float*)d_in[5];
  const float* Wg  = (const float*)d_in[6];
  const float* bg  = (const float*)d_in[7];
  const float* Wo1 = (const float*)d_in[8];
  const float* bo1 = (const float*)d_in[9];
  const float* Wo2 = (const float*)d_in[10];
  const float* bo2 = (const float*)d_in[11];
  const float* Wh1 = (const float*)d_in[12];
  const float* bh1 = (const float*)d_in[13];
  const float* Wh2 = (const float*)d_in[14];
  const float* bh2 = (const float*)d_in[15];
  const float* Wh3 = (const float*)d_in[16];
  const float* bh3 = (const float*)d_in[17];

  const int N = 50000, E = 300000;

  // ---- workspace ----
  auto al = [](size_t b) { return (b + 255) & ~(size_t)255; };
  char* ws = (char*)d_ws;
  size_t off = 0;
  auto alloc = [&](size_t bytes) { char* p = ws + off; off += al(bytes); return p; };

  int*   map    = (int*)alloc((size_t)N * 4);
  int*   meta   = (int*)alloc(256);
  float* deg    = (float*)alloc((size_t)CAPN * 4);
  int*   nodeof = (int*)alloc((size_t)CAPN * 4);
  int*   el0    = (int*)alloc((size_t)CAPE * 4);
  int*   el1    = (int*)alloc((size_t)CAPE * 4);
  int*   el2    = (int*)alloc((size_t)CAPE * 4);
  float* g      = (float*)alloc((size_t)CAPN * HDIM * 4);
  float* hA     = (float*)alloc((size_t)CAPN * HDIM * 4);
  float* hB     = (float*)alloc((size_t)CAPN * HDIM * 4);
  float* headv  = (float*)alloc(4096);
  int*   bar    = (int*)alloc(256);

  if (off > ws_size) {
    k_diag<<<1, 64, 0, stream>>>(out, 9.0e6f + (float)(ws_size >> 20));
    return;
  }

  // barrier slots must start at 0 every call (ws poisoned once with 0xAA)
  hipMemsetAsync(bar, 0, 256, stream);

  k_mega<<<NB, NT, 0, stream>>>(x, ei, ea, tgt, Wi, bi, Wg, bg,
                                Wo1, bo1, Wo2, bo2, Wh1, bh1, Wh2, bh2, Wh3, bh3,
                                N, E, map, meta, deg, nodeof, el0, el1, el2,
                                g, hA, hB, headv, bar, out);
}

// Round 9
// 121.503 us; speedup vs baseline: 3.3489x; 3.3489x over previous
//
#include <hip/hip_runtime.h>

#define HDIM 256
#define CAPN 4096
#define CAPE (CAPN * 8)
#define NT 256

// meta: [0]=slot counter, [5+k]=edge count layer k, no other state.
// map[u]: 0=absent, 1=claim-in-progress, else ((slot+1)<<2)|birth, birth in {0..3}.
// Node u in S_l  <=>  map[u]>=4 && (map[u]&3) >= l  (sets nested S3<=S2<=S1<=S0).

// Per-block edge-index dtype detect: int64 high words (first 64) all zero => stride 2.
__device__ __forceinline__ int detect_stride(const int* __restrict__ ei, int E,
                                             int* s_st, int tid) {
  if (tid < 64) {  // wave 0 exactly
    bool nz = (tid < E) && (ei[2 * tid + 1] != 0);
    unsigned long long b = __ballot(nz);
    if (tid == 0) *s_st = (b != 0ULL) ? 1 : 2;
  }
  __syncthreads();
  return *s_st;
}

// k0: zero map + full-N deg, seed target (slot 0, birth 3), init meta counters.
__global__ void k_init(int* __restrict__ map, float* __restrict__ deg,
                       int* __restrict__ meta, int* __restrict__ nodeof,
                       const int* __restrict__ tgt, int N) {
  int t = tgt[0];
  int gtid = blockIdx.x * blockDim.x + threadIdx.x, gsz = gridDim.x * blockDim.x;
  for (int i = gtid; i < N; i += gsz) { map[i] = (i == t) ? 7 : 0; deg[i] = 0.0f; }
  if (gtid == 0) { meta[0] = 1; meta[5] = 0; meta[6] = 0; meta[7] = 0; nodeof[0] = t; }
}

// k1: blocks [0,128): deg[col] += ea over ALL edges (frontier-independent);
//     blocks [128,256): expansion step l=3 (edges into the target).
#define DEGB 128
__global__ void k_deg_exp3(const int* __restrict__ ei, const float* __restrict__ ea,
                           int E, int* __restrict__ meta, int* __restrict__ map,
                           int* __restrict__ nodeof, int* __restrict__ el2,
                           float* __restrict__ deg) {
  __shared__ int s_st;
  int tid = threadIdx.x;
  int st = detect_stride(ei, E, &s_st, tid);
  if (blockIdx.x < DEGB) {
    int t2 = blockIdx.x * NT + tid, tot = DEGB * NT;
    for (int e = t2; e < E; e += tot)
      atomicAdd(&deg[ei[(size_t)(E + e) * st]], ea[e]);
  } else {
    int t2 = (blockIdx.x - DEGB) * NT + tid, tot = DEGB * NT;
    for (int e = t2; e < E; e += tot) {
      int c = ei[(size_t)(E + e) * st];
      int mv = map[c];
      if (mv >= 4 && (mv & 3) >= 3) {
        int r = ei[(size_t)e * st];
        int s = atomicAdd(&meta[7], 1);
        if (s < CAPE) el2[s] = e;
        if (atomicCAS(&map[r], 0, 1) == 0) {
          int ns = atomicAdd(&meta[0], 1);
          if (ns < CAPN) { nodeof[ns] = r; map[r] = ((ns + 1) << 2) | 2; }
        }
      }
    }
  }
}

// Expansion step l (l=2,1): col in S_l -> record edge (layer l-1), claim row (birth l-1).
__global__ void k_expand(const int* __restrict__ ei, int E, int* __restrict__ meta,
                         int* __restrict__ map, int* __restrict__ nodeof,
                         int* __restrict__ elist, int ecntIdx, int l) {
  __shared__ int s_st;
  int tid = threadIdx.x;
  int st = detect_stride(ei, E, &s_st, tid);
  int e = blockIdx.x * NT + tid;
  if (e >= E) return;
  int c = ei[(size_t)(E + e) * st];
  int mv = map[c];
  if (mv >= 4 && (mv & 3) >= l) {   // mid-kernel claims have birth l-1: excluded
    int r = ei[(size_t)e * st];
    int s = atomicAdd(&meta[ecntIdx], 1);
    if (s < CAPE) elist[s] = e;
    if (atomicCAS(&map[r], 0, 1) == 0) {
      int ns = atomicAdd(&meta[0], 1);
      if (ns < CAPN) { nodeof[ns] = r; map[r] = ((ns + 1) << 2) | (l - 1); }
    }
  }
}

// Layer 0 fused: per 4 rows: h0 = relu(x@Wi+bi) in LDS, g = h0@W0,
// epilogue (rows in S1): hout = b0 + dinv^2 * g.
__global__ void __launch_bounds__(NT) k_l0(
    const int* __restrict__ meta, const int* __restrict__ map,
    const int* __restrict__ nodeof, const float* __restrict__ x,
    const float* __restrict__ Wi, const float* __restrict__ bi,
    const float* __restrict__ W0, const float* __restrict__ b0,
    const float* __restrict__ deg, float* __restrict__ g, float* __restrict__ hout) {
  __shared__ float xs[4][100];
  __shared__ float hs[4][HDIM];
  int ntot = meta[0]; if (ntot > CAPN) ntot = CAPN;
  int tid = threadIdx.x;
  for (int base = blockIdx.x * 4; base < ntot; base += gridDim.x * 4) {
    int nr = ntot - base; if (nr > 4) nr = 4;
    for (int idx = tid; idx < nr * 100; idx += NT) {
      int r = idx / 100, k2 = idx - r * 100;
      xs[r][k2] = x[(size_t)nodeof[base + r] * 100 + k2];
    }
    __syncthreads();
    float a0 = bi[tid], a1 = a0, a2 = a0, a3 = a0;
    for (int k2 = 0; k2 < 100; ++k2) {
      float w = Wi[k2 * HDIM + tid];
      a0 = fmaf(xs[0][k2], w, a0); a1 = fmaf(xs[1][k2], w, a1);
      a2 = fmaf(xs[2][k2], w, a2); a3 = fmaf(xs[3][k2], w, a3);
    }
    hs[0][tid] = fmaxf(a0, 0.f); hs[1][tid] = fmaxf(a1, 0.f);
    hs[2][tid] = fmaxf(a2, 0.f); hs[3][tid] = fmaxf(a3, 0.f);
    __syncthreads();
    float g0 = 0, g1 = 0, g2 = 0, g3 = 0;
    for (int m = 0; m < HDIM; ++m) {
      float w = W0[m * HDIM + tid];
      g0 = fmaf(hs[0][m], w, g0); g1 = fmaf(hs[1][m], w, g1);
      g2 = fmaf(hs[2][m], w, g2); g3 = fmaf(hs[3][m], w, g3);
    }
    float gg[4] = {g0, g1, g2, g3};
    for (int r = 0; r < nr; ++r) {
      int u = nodeof[base + r];
      g[(size_t)(base + r) * HDIM + tid] = gg[r];
      int mv = map[u];
      if ((mv & 3) >= 1) {
        float dv = 1.0f / sqrtf(deg[u] + 1.0f);
        hout[(size_t)(base + r) * HDIM + tid] = b0[tid] + dv * dv * gg[r];
      }
    }
    __syncthreads();
  }
}

// Layers 1,2: per 4 rows: g = relu(hin)@W; epilogue (rows in S_{kk+1}): hout = bk + dinv^2*g.
__global__ void __launch_bounds__(NT) k_gemv4(
    const int* __restrict__ meta, int kk, const int* __restrict__ map,
    const int* __restrict__ nodeof, const float* __restrict__ hin,
    const float* __restrict__ W, const float* __restrict__ bk,
    const float* __restrict__ deg, float* __restrict__ g, float* __restrict__ hout) {
  __shared__ float hs[4][HDIM];
  int ntot = meta[0]; if (ntot > CAPN) ntot = CAPN;
  int tid = threadIdx.x;
  for (int base = blockIdx.x * 4; base < ntot; base += gridDim.x * 4) {
    int nr = ntot - base; if (nr > 4) nr = 4;
    for (int idx = tid; idx < nr * HDIM; idx += NT) {
      int r = idx >> 8, m = idx & 255;
      hs[r][m] = fmaxf(hin[(size_t)(base + r) * HDIM + m], 0.0f);
    }
    __syncthreads();
    float g0 = 0, g1 = 0, g2 = 0, g3 = 0;
    for (int m = 0; m < HDIM; ++m) {
      float w = W[m * HDIM + tid];
      g0 = fmaf(hs[0][m], w, g0); g1 = fmaf(hs[1][m], w, g1);
      g2 = fmaf(hs[2][m], w, g2); g3 = fmaf(hs[3][m], w, g3);
    }
    float gg[4] = {g0, g1, g2, g3};
    for (int r = 0; r < nr; ++r) {
      int u = nodeof[base + r];
      g[(size_t)(base + r) * HDIM + tid] = gg[r];
      int mv = map[u];
      if ((mv & 3) >= kk + 1) {
        float dv = 1.0f / sqrtf(deg[u] + 1.0f);
        hout[(size_t)(base + r) * HDIM + tid] = bk[tid] + dv * dv * gg[r];
      }
    }
    __syncthreads();
  }
}

// hout[slot(col)] += dinv(row)*ea*dinv(col) * g[slot(row)] over layer-k active edges.
__global__ void k_scat(const int* __restrict__ ei, int E, const int* __restrict__ meta,
                       int ecntIdx, const int* __restrict__ elist,
                       const float* __restrict__ ea, const int* __restrict__ map,
                       const float* __restrict__ deg, const float* __restrict__ g,
                       float* __restrict__ hout) {
  __shared__ int s_st;
  int tid = threadIdx.x;
  int st = detect_stride(ei, E, &s_st, tid);
  int ne = meta[ecntIdx]; if (ne > CAPE) ne = CAPE;
  for (int i = blockIdx.x; i < ne; i += gridDim.x) {
    int e = elist[i];
    int u = ei[(size_t)e * st], v = ei[(size_t)(E + e) * st];
    int mu = map[u], mv = map[v];
    if (mu < 4 || mv < 4) continue;   // overflow guard (flagged at tail)
    float du  = 1.0f / sqrtf(deg[u] + 1.0f);
    float dvv = 1.0f / sqrtf(deg[v] + 1.0f);
    float nrm = du * ea[e] * dvv;
    atomicAdd(&hout[(size_t)((mv >> 2) - 1) * HDIM + tid],
              nrm * g[(size_t)((mu >> 2) - 1) * HDIM + tid]);
  }
}

// Head stages 1+2 (proven in round 8): stage1 redundant per block into LDS,
// stage2: block b computes v2[64b..64b+63]. 8 blocks.
__global__ void __launch_bounds__(NT) k_head12(
    const float* __restrict__ h3row, const float* __restrict__ Wo1,
    const float* __restrict__ bo1, const float* __restrict__ Wo2,
    const float* __restrict__ bo2, float* __restrict__ v2) {
  __shared__ float vs[256];
  __shared__ float v1s[512];
  __shared__ float red[256];
  int tid = threadIdx.x;
  vs[tid] = h3row[tid];
  __syncthreads();
  for (int j = tid; j < 512; j += NT) {
    float a = bo1[j];
#pragma unroll 4
    for (int k = 0; k < 256; ++k) a = fmaf(vs[k], Wo1[(size_t)k * 512 + j], a);
    v1s[j] = fmaxf(a, 0.0f);
  }
  __syncthreads();
  int tx = tid & 63, ty = tid >> 6;
  int j = blockIdx.x * 64 + tx;
  float acc = 0.0f;
#pragma unroll 4
  for (int k = ty * 128; k < ty * 128 + 128; ++k)
    acc = fmaf(v1s[k], Wo2[(size_t)k * 512 + j], acc);
  red[ty * 64 + tx] = acc;
  __syncthreads();
  if (ty == 0)
    v2[j] = red[tx] + red[64 + tx] + red[128 + tx] + red[192 + tx] + bo2[j];
}

// Tail (proven in round 8): v3=relu(v2@Wh1+bh1), v4=relu(v3@Wh2+bh2), out=v4@Wh3+bh3.
// Side-channel: capacity overflow -> out[4] = code*1e6.
__global__ void __launch_bounds__(NT) k_tail(
    const float* __restrict__ v2, const float* __restrict__ Wh1,
    const float* __restrict__ bh1, const float* __restrict__ Wh2,
    const float* __restrict__ bh2, const float* __restrict__ Wh3,
    const float* __restrict__ bh3, const int* __restrict__ meta,
    float* __restrict__ out) {
  __shared__ float v2s[512];
  __shared__ float v3s[256];
  __shared__ float part[256];
  int tid = threadIdx.x;
  v2s[tid] = v2[tid];
  v2s[tid + 256] = v2[tid + 256];
  __syncthreads();
  float a3 = bh1[tid];
#pragma unroll 4
  for (int k = 0; k < 512; ++k) a3 = fmaf(v2s[k], Wh1[(size_t)k * 256 + tid], a3);
  v3s[tid] = fmaxf(a3, 0.0f);
  __syncthreads();
  int o = tid & 127, half = tid >> 7;
  float acc = 0.0f;
#pragma unroll 4
  for (int k = half * 128; k < half * 128 + 128; ++k)
    acc = fmaf(v3s[k], Wh2[(size_t)k * 128 + o], acc);
  part[tid] = acc;
  __syncthreads();
  if (tid < 128) v2s[tid] = fmaxf(part[tid] + part[tid + 128] + bh2[tid], 0.0f);
  __syncthreads();
  if (tid < 5) {
    float a = bh3[tid];
#pragma unroll 4
    for (int k = 0; k < 128; ++k) a = fmaf(v2s[k], Wh3[k * 5 + tid], a);
    if (tid == 4) {
      int B = 0;
      if (meta[0] > CAPN) B |= 1;
      if (meta[5] > CAPE || meta[6] > CAPE || meta[7] > CAPE) B |= 2;
      if (B) a = 1.0e6f * (float)B;
    }
    out[tid] = a;
  }
}

// Diagnostic: out = [0,0,0,0,D]
__global__ void k_diag(float* __restrict__ out, float D) {
  int tid = threadIdx.x;
  if (tid < 4) out[tid] = 0.0f;
  if (tid == 4) out[tid] = D;
}

extern "C" void kernel_launch(void* const* d_in, const int* in_sizes, int n_in,
                              void* d_out, int out_size, void* d_ws, size_t ws_size,
                              hipStream_t stream) {
  float* out = (float*)d_out;

  // ---- input-mapping tripwire (proven good) ----
  static const long long EXP[18] = {5000000, 600000, 300000, 1, 25600, 256, 196608, 768,
                                    131072, 512, 262144, 512, 131072, 256, 32768, 128, 640, 5};
  if (n_in != 18) {
    k_diag<<<1, 64, 0, stream>>>(out, 3.0e6f + 1000.0f * (float)n_in);
    return;
  }
  for (int i = 0; i < 18; ++i) {
    long long s = in_sizes[i];
    bool ok = (s == EXP[i]) || (i == 1 && s == 2 * EXP[1]);
    if (!ok) {
      k_diag<<<1, 64, 0, stream>>>(out, (float)(i + 1) * 1.0e5f);
      return;
    }
  }

  const float* x   = (const float*)d_in[0];
  const int*   ei  = (const int*)d_in[1];
  const float* ea  = (const float*)d_in[2];
  const int*   tgt = (const int*)d_in[3];
  const float* Wi  = (const float*)d_in[4];
  const float* bi  = (const float*)d_in[5];
  const float* Wg  = (const float*)d_in[6];
  const float* bg  = (const float*)d_in[7];
  const float* Wo1 = (const float*)d_in[8];
  const float* bo1 = (const float*)d_in[9];
  const float* Wo2 = (const float*)d_in[10];
  const float* bo2 = (const float*)d_in[11];
  const float* Wh1 = (const float*)d_in[12];
  const float* bh1 = (const float*)d_in[13];
  const float* Wh2 = (const float*)d_in[14];
  const float* bh2 = (const float*)d_in[15];
  const float* Wh3 = (const float*)d_in[16];
  const float* bh3 = (const float*)d_in[17];

  const int N = 50000, E = 300000;

  // ---- workspace ----
  auto al = [](size_t b) { return (b + 255) & ~(size_t)255; };
  char* ws = (char*)d_ws;
  size_t off = 0;
  auto alloc = [&](size_t bytes) { char* p = ws + off; off += al(bytes); return p; };

  int*   map    = (int*)alloc((size_t)N * 4);
  int*   meta   = (int*)alloc(256);
  float* deg    = (float*)alloc((size_t)N * 4);       // full-N degree
  int*   nodeof = (int*)alloc((size_t)CAPN * 4);
  int*   el0    = (int*)alloc((size_t)CAPE * 4);
  int*   el1    = (int*)alloc((size_t)CAPE * 4);
  int*   el2    = (int*)alloc((size_t)CAPE * 4);
  float* g      = (float*)alloc((size_t)CAPN * HDIM * 4);
  float* hA     = (float*)alloc((size_t)CAPN * HDIM * 4);
  float* hB     = (float*)alloc((size_t)CAPN * HDIM * 4);
  float* headv  = (float*)alloc(4096);

  if (off > ws_size) {
    k_diag<<<1, 64, 0, stream>>>(out, 9.0e6f + (float)(ws_size >> 20));
    return;
  }

  dim3 b256(NT);
  int gE = (E + NT - 1) / NT;

  // 12 dispatches total
  k_init<<<256, b256, 0, stream>>>(map, deg, meta, nodeof, tgt, N);
  k_deg_exp3<<<256, b256, 0, stream>>>(ei, ea, E, meta, map, nodeof, el2, deg);
  k_expand<<<gE, b256, 0, stream>>>(ei, E, meta, map, nodeof, el1, 6, 2);
  k_expand<<<gE, b256, 0, stream>>>(ei, E, meta, map, nodeof, el0, 5, 1);

  const float* W0 = Wg;
  const float* b0 = bg;
  k_l0<<<256, b256, 0, stream>>>(meta, map, nodeof, x, Wi, bi, W0, b0, deg, g, hA);
  k_scat<<<256, b256, 0, stream>>>(ei, E, meta, 5, el0, ea, map, deg, g, hA);

  k_gemv4<<<256, b256, 0, stream>>>(meta, 1, map, nodeof, hA,
                                    Wg + (size_t)1 * HDIM * HDIM, bg + HDIM, deg, g, hB);
  k_scat<<<256, b256, 0, stream>>>(ei, E, meta, 6, el1, ea, map, deg, g, hB);

  k_gemv4<<<256, b256, 0, stream>>>(meta, 2, map, nodeof, hB,
                                    Wg + (size_t)2 * HDIM * HDIM, bg + 2 * HDIM, deg, g, hA);
  k_scat<<<256, b256, 0, stream>>>(ei, E, meta, 7, el2, ea, map, deg, g, hA);
  // hA row 0 = target's h3 (slot 0 seeded at birth)

  k_head12<<<8, b256, 0, stream>>>(hA, Wo1, bo1, Wo2, bo2, headv);
  k_tail<<<1, b256, 0, stream>>>(headv, Wh1, bh1, Wh2, bh2, Wh3, bh3, meta, out);
}

// Round 10
// 99.806 us; speedup vs baseline: 4.0769x; 1.2174x over previous
//
#include <hip/hip_runtime.h>

#define HDIM 256
#define CAPN 4096
#define CAPE (CAPN * 8)
#define NT 256

// meta: [0]=slot counter, [5+k]=edge count layer k.
// map[u]: 0=absent, 1=claim-in-progress, else ((slot+1)<<2)|birth, birth in {0..3}.
// Node u in S_l  <=>  map[u]>=4 && (map[u]&3) >= l  (sets nested S3<=S2<=S1<=S0).

// Per-block edge-index dtype detect: int64 high words (first 64) all zero => stride 2.
__device__ __forceinline__ int detect_stride(const int* __restrict__ ei, int E,
                                             int* s_st, int tid) {
  if (tid < 64) {  // wave 0 exactly
    bool nz = (tid < E) && (ei[2 * tid + 1] != 0);
    unsigned long long b = __ballot(nz);
    if (tid == 0) *s_st = (b != 0ULL) ? 1 : 2;
  }
  __syncthreads();
  return *s_st;
}

// k0: zero map + full-N deg, seed target (slot 0, birth 3), init meta counters.
__global__ void k_init(int* __restrict__ map, float* __restrict__ deg,
                       int* __restrict__ meta, int* __restrict__ nodeof,
                       const int* __restrict__ tgt, int N) {
  int t = tgt[0];
  int gtid = blockIdx.x * blockDim.x + threadIdx.x, gsz = gridDim.x * blockDim.x;
  for (int i = gtid; i < N; i += gsz) { map[i] = (i == t) ? 7 : 0; deg[i] = 0.0f; }
  if (gtid == 0) { meta[0] = 1; meta[5] = 0; meta[6] = 0; meta[7] = 0; nodeof[0] = t; }
}

// k1: blocks [0,128): deg[col] += ea over ALL edges (frontier-independent);
//     blocks [128,256): expansion step l=3 (edges into the target).
#define DEGB 128
__global__ void k_deg_exp3(const int* __restrict__ ei, const float* __restrict__ ea,
                           int E, int* __restrict__ meta, int* __restrict__ map,
                           int* __restrict__ nodeof, int* __restrict__ el2,
                           float* __restrict__ deg) {
  __shared__ int s_st;
  int tid = threadIdx.x;
  int st = detect_stride(ei, E, &s_st, tid);
  if (blockIdx.x < DEGB) {
    int t2 = blockIdx.x * NT + tid, tot = DEGB * NT;
    for (int e = t2; e < E; e += tot)
      atomicAdd(&deg[ei[(size_t)(E + e) * st]], ea[e]);
  } else {
    int t2 = (blockIdx.x - DEGB) * NT + tid, tot = DEGB * NT;
    for (int e = t2; e < E; e += tot) {
      int c = ei[(size_t)(E + e) * st];
      int mv = map[c];
      if (mv >= 4 && (mv & 3) >= 3) {
        int r = ei[(size_t)e * st];
        int s = atomicAdd(&meta[7], 1);
        if (s < CAPE) el2[s] = e;
        if (atomicCAS(&map[r], 0, 1) == 0) {
          int ns = atomicAdd(&meta[0], 1);
          if (ns < CAPN) { nodeof[ns] = r; map[r] = ((ns + 1) << 2) | 2; }
        }
      }
    }
  }
}

// Expansion step l (l=2,1): col in S_l -> record edge (layer l-1), claim row (birth l-1).
__global__ void k_expand(const int* __restrict__ ei, int E, int* __restrict__ meta,
                         int* __restrict__ map, int* __restrict__ nodeof,
                         int* __restrict__ elist, int ecntIdx, int l) {
  __shared__ int s_st;
  int tid = threadIdx.x;
  int st = detect_stride(ei, E, &s_st, tid);
  int e = blockIdx.x * NT + tid;
  if (e >= E) return;
  int c = ei[(size_t)(E + e) * st];
  int mv = map[c];
  if (mv >= 4 && (mv & 3) >= l) {   // mid-kernel claims have birth l-1: excluded
    int r = ei[(size_t)e * st];
    int s = atomicAdd(&meta[ecntIdx], 1);
    if (s < CAPE) elist[s] = e;
    if (atomicCAS(&map[r], 0, 1) == 0) {
      int ns = atomicAdd(&meta[0], 1);
      if (ns < CAPN) { nodeof[ns] = r; map[r] = ((ns + 1) << 2) | (l - 1); }
    }
  }
}

// Layer 0 fused: per 4 rows: h0 = relu(x@Wi+bi) in LDS, g = h0@W0,
// epilogue (rows in S1): hout = b0 + dinv^2 * g.
__global__ void __launch_bounds__(NT) k_l0(
    const int* __restrict__ meta, const int* __restrict__ map,
    const int* __restrict__ nodeof, const float* __restrict__ x,
    const float* __restrict__ Wi, const float* __restrict__ bi,
    const float* __restrict__ W0, const float* __restrict__ b0,
    const float* __restrict__ deg, float* __restrict__ g, float* __restrict__ hout) {
  __shared__ float xs[4][100];
  __shared__ float hs[4][HDIM];
  int ntot = meta[0]; if (ntot > CAPN) ntot = CAPN;
  int tid = threadIdx.x;
  for (int base = blockIdx.x * 4; base < ntot; base += gridDim.x * 4) {
    int nr = ntot - base; if (nr > 4) nr = 4;
    for (int idx = tid; idx < nr * 100; idx += NT) {
      int r = idx / 100, k2 = idx - r * 100;
      xs[r][k2] = x[(size_t)nodeof[base + r] * 100 + k2];
    }
    __syncthreads();
    float a0 = bi[tid], a1 = a0, a2 = a0, a3 = a0;
    for (int k2 = 0; k2 < 100; ++k2) {
      float w = Wi[k2 * HDIM + tid];
      a0 = fmaf(xs[0][k2], w, a0); a1 = fmaf(xs[1][k2], w, a1);
      a2 = fmaf(xs[2][k2], w, a2); a3 = fmaf(xs[3][k2], w, a3);
    }
    hs[0][tid] = fmaxf(a0, 0.f); hs[1][tid] = fmaxf(a1, 0.f);
    hs[2][tid] = fmaxf(a2, 0.f); hs[3][tid] = fmaxf(a3, 0.f);
    __syncthreads();
    float g0 = 0, g1 = 0, g2 = 0, g3 = 0;
    for (int m = 0; m < HDIM; ++m) {
      float w = W0[m * HDIM + tid];
      g0 = fmaf(hs[0][m], w, g0); g1 = fmaf(hs[1][m], w, g1);
      g2 = fmaf(hs[2][m], w, g2); g3 = fmaf(hs[3][m], w, g3);
    }
    float gg[4] = {g0, g1, g2, g3};
    for (int r = 0; r < nr; ++r) {
      int u = nodeof[base + r];
      g[(size_t)(base + r) * HDIM + tid] = gg[r];
      int mv = map[u];
      if ((mv & 3) >= 1) {
        float dv = 1.0f / sqrtf(deg[u] + 1.0f);
        hout[(size_t)(base + r) * HDIM + tid] = b0[tid] + dv * dv * gg[r];
      }
    }
    __syncthreads();
  }
}

// Layers 1,2: per 4 rows: g = relu(hin)@W; epilogue (rows in S_{kk+1}): hout = bk + dinv^2*g.
__global__ void __launch_bounds__(NT) k_gemv4(
    const int* __restrict__ meta, int kk, const int* __restrict__ map,
    const int* __restrict__ nodeof, const float* __restrict__ hin,
    const float* __restrict__ W, const float* __restrict__ bk,
    const float* __restrict__ deg, float* __restrict__ g, float* __restrict__ hout) {
  __shared__ float hs[4][HDIM];
  int ntot = meta[0]; if (ntot > CAPN) ntot = CAPN;
  int tid = threadIdx.x;
  for (int base = blockIdx.x * 4; base < ntot; base += gridDim.x * 4) {
    int nr = ntot - base; if (nr > 4) nr = 4;
    for (int idx = tid; idx < nr * HDIM; idx += NT) {
      int r = idx >> 8, m = idx & 255;
      hs[r][m] = fmaxf(hin[(size_t)(base + r) * HDIM + m], 0.0f);
    }
    __syncthreads();
    float g0 = 0, g1 = 0, g2 = 0, g3 = 0;
    for (int m = 0; m < HDIM; ++m) {
      float w = W[m * HDIM + tid];
      g0 = fmaf(hs[0][m], w, g0); g1 = fmaf(hs[1][m], w, g1);
      g2 = fmaf(hs[2][m], w, g2); g3 = fmaf(hs[3][m], w, g3);
    }
    float gg[4] = {g0, g1, g2, g3};
    for (int r = 0; r < nr; ++r) {
      int u = nodeof[base + r];
      g[(size_t)(base + r) * HDIM + tid] = gg[r];
      int mv = map[u];
      if ((mv & 3) >= kk + 1) {
        float dv = 1.0f / sqrtf(deg[u] + 1.0f);
        hout[(size_t)(base + r) * HDIM + tid] = bk[tid] + dv * dv * gg[r];
      }
    }
    __syncthreads();
  }
}

// hout[slot(col)] += dinv(row)*ea*dinv(col) * g[slot(row)] over layer-k active edges.
__global__ void k_scat(const int* __restrict__ ei, int E, const int* __restrict__ meta,
                       int ecntIdx, const int* __restrict__ elist,
                       const float* __restrict__ ea, const int* __restrict__ map,
                       const float* __restrict__ deg, const float* __restrict__ g,
                       float* __restrict__ hout) {
  __shared__ int s_st;
  int tid = threadIdx.x;
  int st = detect_stride(ei, E, &s_st, tid);
  int ne = meta[ecntIdx]; if (ne > CAPE) ne = CAPE;
  for (int i = blockIdx.x; i < ne; i += gridDim.x) {
    int e = elist[i];
    int u = ei[(size_t)e * st], v = ei[(size_t)(E + e) * st];
    int mu = map[u], mv = map[v];
    if (mu < 4 || mv < 4) continue;   // overflow guard (flagged at tail)
    float du  = 1.0f / sqrtf(deg[u] + 1.0f);
    float dvv = 1.0f / sqrtf(deg[v] + 1.0f);
    float nrm = du * ea[e] * dvv;
    atomicAdd(&hout[(size_t)((mv >> 2) - 1) * HDIM + tid],
              nrm * g[(size_t)((mu >> 2) - 1) * HDIM + tid]);
  }
}

// Head MLP stage (proven rounds 1-7): vout[j] = act(vin @ W + b);
// 64 outputs x 4 K-chunks per 256-thread block, KOUT/64 blocks. W read exactly once.
template <int KIN, int KOUT, bool RELU>
__global__ void __launch_bounds__(256) k_head(const float* __restrict__ vin,
                                              const float* __restrict__ W,
                                              const float* __restrict__ b,
                                              float* __restrict__ vout) {
  __shared__ float vs[KIN];
  __shared__ float red[4][64];
  int tx = threadIdx.x & 63, ty = threadIdx.x >> 6;
  for (int k = threadIdx.x; k < KIN; k += 256) vs[k] = vin[k];
  __syncthreads();
  int j = blockIdx.x * 64 + tx;
  const int KQ = KIN / 4;
  float acc = 0.0f;
#pragma unroll 4
  for (int k = ty * KQ; k < (ty + 1) * KQ; ++k) acc = fmaf(vs[k], W[(size_t)k * KOUT + j], acc);
  red[ty][tx] = acc;
  __syncthreads();
  if (ty == 0) {
    float r = red[0][tx] + red[1][tx] + red[2][tx] + red[3][tx] + b[j];
    vout[j] = RELU ? fmaxf(r, 0.0f) : r;
  }
}

// Tail (proven rounds 6-7): v4 = relu(v3 @ Wh2 + bh2) [256->128], out = v4 @ Wh3 + bh3.
// One block, only 131 KB of weights. Side-channel: overflow -> out[4] = code*1e6.
__global__ void __launch_bounds__(NT) k_tail(
    const float* __restrict__ vin, const float* __restrict__ Wh2,
    const float* __restrict__ bh2, const float* __restrict__ Wh3,
    const float* __restrict__ bh3, const int* __restrict__ meta,
    float* __restrict__ out) {
  __shared__ float vs[256];
  __shared__ float part[256];
  __shared__ float v4[128];
  int tid = threadIdx.x;
  vs[tid] = vin[tid];
  __syncthreads();
  int o = tid & 127, half = tid >> 7;
  float acc = 0.0f;
#pragma unroll 4
  for (int k = half * 128; k < half * 128 + 128; ++k)
    acc = fmaf(vs[k], Wh2[(size_t)k * 128 + o], acc);
  part[tid] = acc;
  __syncthreads();
  if (tid < 128) v4[tid] = fmaxf(part[tid] + part[tid + 128] + bh2[tid], 0.0f);
  __syncthreads();
  if (tid < 5) {
    float a = bh3[tid];
#pragma unroll 4
    for (int k = 0; k < 128; ++k) a = fmaf(v4[k], Wh3[k * 5 + tid], a);
    if (tid == 4) {
      int B = 0;
      if (meta[0] > CAPN) B |= 1;
      if (meta[5] > CAPE || meta[6] > CAPE || meta[7] > CAPE) B |= 2;
      if (B) a = 1.0e6f * (float)B;
    }
    out[tid] = a;
  }
}

// Diagnostic: out = [0,0,0,0,D]
__global__ void k_diag(float* __restrict__ out, float D) {
  int tid = threadIdx.x;
  if (tid < 4) out[tid] = 0.0f;
  if (tid == 4) out[tid] = D;
}

extern "C" void kernel_launch(void* const* d_in, const int* in_sizes, int n_in,
                              void* d_out, int out_size, void* d_ws, size_t ws_size,
                              hipStream_t stream) {
  float* out = (float*)d_out;

  // ---- input-mapping tripwire (proven good) ----
  static const long long EXP[18] = {5000000, 600000, 300000, 1, 25600, 256, 196608, 768,
                                    131072, 512, 262144, 512, 131072, 256, 32768, 128, 640, 5};
  if (n_in != 18) {
    k_diag<<<1, 64, 0, stream>>>(out, 3.0e6f + 1000.0f * (float)n_in);
    return;
  }
  for (int i = 0; i < 18; ++i) {
    long long s = in_sizes[i];
    bool ok = (s == EXP[i]) || (i == 1 && s == 2 * EXP[1]);
    if (!ok) {
      k_diag<<<1, 64, 0, stream>>>(out, (float)(i + 1) * 1.0e5f);
      return;
    }
  }

  const float* x   = (const float*)d_in[0];
  const int*   ei  = (const int*)d_in[1];
  const float* ea  = (const float*)d_in[2];
  const int*   tgt = (const int*)d_in[3];
  const float* Wi  = (const float*)d_in[4];
  const float* bi  = (const float*)d_in[5];
  const float* Wg  = (const float*)d_in[6];
  const float* bg  = (const float*)d_in[7];
  const float* Wo1 = (const float*)d_in[8];
  const float* bo1 = (const float*)d_in[9];
  const float* Wo2 = (const float*)d_in[10];
  const float* bo2 = (const float*)d_in[11];
  const float* Wh1 = (const float*)d_in[12];
  const float* bh1 = (const float*)d_in[13];
  const float* Wh2 = (const float*)d_in[14];
  const float* bh2 = (const float*)d_in[15];
  const float* Wh3 = (const float*)d_in[16];
  const float* bh3 = (const float*)d_in[17];

  const int N = 50000, E = 300000;

  // ---- workspace ----
  auto al = [](size_t b) { return (b + 255) & ~(size_t)255; };
  char* ws = (char*)d_ws;
  size_t off = 0;
  auto alloc = [&](size_t bytes) { char* p = ws + off; off += al(bytes); return p; };

  int*   map    = (int*)alloc((size_t)N * 4);
  int*   meta   = (int*)alloc(256);
  float* deg    = (float*)alloc((size_t)N * 4);       // full-N degree
  int*   nodeof = (int*)alloc((size_t)CAPN * 4);
  int*   el0    = (int*)alloc((size_t)CAPE * 4);
  int*   el1    = (int*)alloc((size_t)CAPE * 4);
  int*   el2    = (int*)alloc((size_t)CAPE * 4);
  float* g      = (float*)alloc((size_t)CAPN * HDIM * 4);
  float* hA     = (float*)alloc((size_t)CAPN * HDIM * 4);
  float* hB     = (float*)alloc((size_t)CAPN * HDIM * 4);
  float* headv  = (float*)alloc(4096);
  float* v1 = headv;
  float* v2 = headv + 512;

  if (off > ws_size) {
    k_diag<<<1, 64, 0, stream>>>(out, 9.0e6f + (float)(ws_size >> 20));
    return;
  }

  dim3 b256(NT);
  int gE = (E + NT - 1) / NT;

  // 13 dispatches total
  k_init<<<256, b256, 0, stream>>>(map, deg, meta, nodeof, tgt, N);
  k_deg_exp3<<<256, b256, 0, stream>>>(ei, ea, E, meta, map, nodeof, el2, deg);
  k_expand<<<gE, b256, 0, stream>>>(ei, E, meta, map, nodeof, el1, 6, 2);
  k_expand<<<gE, b256, 0, stream>>>(ei, E, meta, map, nodeof, el0, 5, 1);

  k_l0<<<256, b256, 0, stream>>>(meta, map, nodeof, x, Wi, bi, Wg, bg, deg, g, hA);
  k_scat<<<256, b256, 0, stream>>>(ei, E, meta, 5, el0, ea, map, deg, g, hA);

  k_gemv4<<<256, b256, 0, stream>>>(meta, 1, map, nodeof, hA,
                                    Wg + (size_t)1 * HDIM * HDIM, bg + HDIM, deg, g, hB);
  k_scat<<<256, b256, 0, stream>>>(ei, E, meta, 6, el1, ea, map, deg, g, hB);

  k_gemv4<<<256, b256, 0, stream>>>(meta, 2, map, nodeof, hB,
                                    Wg + (size_t)2 * HDIM * HDIM, bg + 2 * HDIM, deg, g, hA);
  k_scat<<<256, b256, 0, stream>>>(ei, E, meta, 7, el2, ea, map, deg, g, hA);
  // hA row 0 = target's h3 (slot 0 seeded at birth)

  // head MLP, parallel per-stage kernels (proven structure, W read exactly once)
  k_head<256, 512, true ><<<8, b256, 0, stream>>>(hA, Wo1, bo1, v1);
  k_head<512, 512, false><<<8, b256, 0, stream>>>(v1, Wo2, bo2, v2);
  k_head<512, 256, true ><<<4, b256, 0, stream>>>(v2, Wh1, bh1, v1);
  k_tail<<<1, b256, 0, stream>>>(v1, Wh2, bh2, Wh3, bh3, meta, out);
}

// Round 11
// 83.527 us; speedup vs baseline: 4.8716x; 1.1949x over previous
//
#include <hip/hip_runtime.h>

#define HDIM 256
#define CAPN 4096
#define CAPE (CAPN * 8)
#define NT 256

// meta: [0]=slot counter, [5+k]=edge count layer k.
// map[u]: 0=absent, 1=claim-in-progress, else ((slot+1)<<2)|birth, birth in {0..3}.
// Node u in S_l <=> map[u]>=4 && (map[u]&3) >= l. Sets nested; slots birth-ordered
// (descending) because claims happen level-by-level.

__device__ __forceinline__ float4 fma4(float s, float4 w, float4 a) {
  a.x = fmaf(s, w.x, a.x); a.y = fmaf(s, w.y, a.y);
  a.z = fmaf(s, w.z, a.z); a.w = fmaf(s, w.w, a.w);
  return a;
}

// Per-block edge-index dtype detect: int64 high words (first 64) all zero => stride 2.
__device__ __forceinline__ int detect_stride(const int* __restrict__ ei, int E,
                                             int* s_st, int tid) {
  if (tid < 64) {
    bool nz = (tid < E) && (ei[2 * tid + 1] != 0);
    unsigned long long b = __ballot(nz);
    if (tid == 0) *s_st = (b != 0ULL) ? 1 : 2;
  }
  __syncthreads();
  return *s_st;
}

// k0: zero map + full-N deg, seed target (slot 0, birth 3), init meta counters.
__global__ void k_init(int* __restrict__ map, float* __restrict__ deg,
                       int* __restrict__ meta, int* __restrict__ nodeof,
                       const int* __restrict__ tgt, int N) {
  int t = tgt[0];
  int gtid = blockIdx.x * blockDim.x + threadIdx.x, gsz = gridDim.x * blockDim.x;
  for (int i = gtid; i < N; i += gsz) { map[i] = (i == t) ? 7 : 0; deg[i] = 0.0f; }
  if (gtid == 0) { meta[0] = 1; meta[5] = 0; meta[6] = 0; meta[7] = 0; nodeof[0] = t; }
}

// k1: blocks [0,128): deg[col] += ea over ALL edges; blocks [128,256): expansion l=3.
#define DEGB 128
__global__ void k_deg_exp3(const int* __restrict__ ei, const float* __restrict__ ea,
                           int E, int* __restrict__ meta, int* __restrict__ map,
                           int* __restrict__ nodeof, int* __restrict__ el2,
                           float* __restrict__ deg) {
  __shared__ int s_st;
  int tid = threadIdx.x;
  int st = detect_stride(ei, E, &s_st, tid);
  if (blockIdx.x < DEGB) {
    int t2 = blockIdx.x * NT + tid, tot = DEGB * NT;
    for (int e = t2; e < E; e += tot)
      atomicAdd(&deg[ei[(size_t)(E + e) * st]], ea[e]);
  } else {
    int t2 = (blockIdx.x - DEGB) * NT + tid, tot = DEGB * NT;
    for (int e = t2; e < E; e += tot) {
      int c = ei[(size_t)(E + e) * st];
      int mv = map[c];
      if (mv >= 4 && (mv & 3) >= 3) {
        int r = ei[(size_t)e * st];
        int s = atomicAdd(&meta[7], 1);
        if (s < CAPE) el2[s] = e;
        if (atomicCAS(&map[r], 0, 1) == 0) {
          int ns = atomicAdd(&meta[0], 1);
          if (ns < CAPN) { nodeof[ns] = r; map[r] = ((ns + 1) << 2) | 2; }
        }
      }
    }
  }
}

// Expansion step l (l=2,1): col in S_l -> record edge (layer l-1), claim row (birth l-1).
__global__ void k_expand(const int* __restrict__ ei, int E, int* __restrict__ meta,
                         int* __restrict__ map, int* __restrict__ nodeof,
                         int* __restrict__ elist, int ecntIdx, int l) {
  __shared__ int s_st;
  int tid = threadIdx.x;
  int st = detect_stride(ei, E, &s_st, tid);
  int e = blockIdx.x * NT + tid;
  if (e >= E) return;
  int c = ei[(size_t)(E + e) * st];
  int mv = map[c];
  if (mv >= 4 && (mv & 3) >= l) {
    int r = ei[(size_t)e * st];
    int s = atomicAdd(&meta[ecntIdx], 1);
    if (s < CAPE) elist[s] = e;
    if (atomicCAS(&map[r], 0, 1) == 0) {
      int ns = atomicAdd(&meta[0], 1);
      if (ns < CAPN) { nodeof[ns] = r; map[r] = ((ns + 1) << 2) | (l - 1); }
    }
  }
}

// Layer 0, float4: per 4 rows: h0 = relu(x@Wi+bi) (LDS), g = h0@W0,
// epilogue rows in S1: hout = b0 + dinv^2 * g.  Thread = (quad q, K-group kg).
__global__ void __launch_bounds__(NT) k_l0q(
    const int* __restrict__ meta, const int* __restrict__ map,
    const int* __restrict__ nodeof, const float* __restrict__ x,
    const float* __restrict__ Wi, const float* __restrict__ bi,
    const float* __restrict__ W0, const float* __restrict__ b0,
    const float* __restrict__ deg, float* __restrict__ g, float* __restrict__ hout) {
  __shared__ float xs[4][112];
  __shared__ float hs[4][HDIM];
  __shared__ float4 red[4][4][64];  // [row][kg][quad]
  const float4* Wi4 = (const float4*)Wi;
  const float4* W04 = (const float4*)W0;
  const float4* bi4 = (const float4*)bi;
  const float4* b04 = (const float4*)b0;
  float4* g4 = (float4*)g;
  float4* hout4 = (float4*)hout;
  int ntot = meta[0]; if (ntot > CAPN) ntot = CAPN;
  int tid = threadIdx.x, q = tid & 63, kg = tid >> 6;
  for (int base = blockIdx.x * 4; base < ntot; base += gridDim.x * 4) {
    int nr = ntot - base; if (nr > 4) nr = 4;
    for (int idx = tid; idx < nr * 100; idx += NT) {
      int r = idx / 100, k2 = idx - r * 100;
      xs[r][k2] = x[(size_t)nodeof[base + r] * 100 + k2];
    }
    __syncthreads();
    {  // h0 = relu(x @ Wi + bi), K=100 split 4x25
      float4 a0 = {0,0,0,0}, a1 = a0, a2 = a0, a3 = a0;
#pragma unroll 5
      for (int k2 = kg * 25; k2 < kg * 25 + 25; ++k2) {
        float4 w = Wi4[(size_t)k2 * 64 + q];
        a0 = fma4(xs[0][k2], w, a0); a1 = fma4(xs[1][k2], w, a1);
        a2 = fma4(xs[2][k2], w, a2); a3 = fma4(xs[3][k2], w, a3);
      }
      red[0][kg][q] = a0; red[1][kg][q] = a1; red[2][kg][q] = a2; red[3][kg][q] = a3;
    }
    __syncthreads();
    if (tid < 64) {
      float4 bb = bi4[tid];
      for (int r = 0; r < nr; ++r) {
        float4 s = red[r][0][tid], s1 = red[r][1][tid], s2 = red[r][2][tid], s3 = red[r][3][tid];
        s.x = fmaxf(s.x + s1.x + s2.x + s3.x + bb.x, 0.0f);
        s.y = fmaxf(s.y + s1.y + s2.y + s3.y + bb.y, 0.0f);
        s.z = fmaxf(s.z + s1.z + s2.z + s3.z + bb.z, 0.0f);
        s.w = fmaxf(s.w + s1.w + s2.w + s3.w + bb.w, 0.0f);
        *(float4*)&hs[r][tid * 4] = s;
      }
    }
    __syncthreads();
    {  // g = h0 @ W0, K=256 split 4x64
      float4 a0 = {0,0,0,0}, a1 = a0, a2 = a0, a3 = a0;
#pragma unroll 4
      for (int m = kg * 64; m < kg * 64 + 64; ++m) {
        float4 w = W04[(size_t)m * 64 + q];
        a0 = fma4(hs[0][m], w, a0); a1 = fma4(hs[1][m], w, a1);
        a2 = fma4(hs[2][m], w, a2); a3 = fma4(hs[3][m], w, a3);
      }
      red[0][kg][q] = a0; red[1][kg][q] = a1; red[2][kg][q] = a2; red[3][kg][q] = a3;
    }
    __syncthreads();
    if (tid < 64) {
      float4 bb = b04[tid];
      for (int r = 0; r < nr; ++r) {
        float4 s = red[r][0][tid], s1 = red[r][1][tid], s2 = red[r][2][tid], s3 = red[r][3][tid];
        s.x += s1.x + s2.x + s3.x; s.y += s1.y + s2.y + s3.y;
        s.z += s1.z + s2.z + s3.z; s.w += s1.w + s2.w + s3.w;
        g4[(size_t)(base + r) * 64 + tid] = s;
        int u = nodeof[base + r];
        int mv = map[u];
        if ((mv & 3) >= 1) {
          float dv = 1.0f / sqrtf(deg[u] + 1.0f);
          float d2 = dv * dv;
          float4 h;
          h.x = bb.x + d2 * s.x; h.y = bb.y + d2 * s.y;
          h.z = bb.z + d2 * s.z; h.w = bb.w + d2 * s.w;
          hout4[(size_t)(base + r) * 64 + tid] = h;
        }
      }
    }
    __syncthreads();
  }
}

// Layers 1,2, float4 + birth-skip: g = relu(hin)@W for rows with birth>=kk (slot-prefix);
// epilogue rows in S_{kk+1}: hout = bk + dinv^2*g.
__global__ void __launch_bounds__(NT) k_gemv4q(
    const int* __restrict__ meta, int kk, const int* __restrict__ map,
    const int* __restrict__ nodeof, const float* __restrict__ hin,
    const float* __restrict__ W, const float* __restrict__ bk,
    const float* __restrict__ deg, float* __restrict__ g, float* __restrict__ hout) {
  __shared__ float hs[4][HDIM];
  __shared__ float4 red[4][4][64];
  const float4* W4 = (const float4*)W;
  const float4* bk4 = (const float4*)bk;
  const float4* hin4 = (const float4*)hin;
  float4* g4 = (float4*)g;
  float4* hout4 = (float4*)hout;
  int ntot = meta[0]; if (ntot > CAPN) ntot = CAPN;
  int tid = threadIdx.x, q = tid & 63, kg = tid >> 6;
  for (int base = blockIdx.x * 4; base < ntot; base += gridDim.x * 4) {
    int nr = ntot - base; if (nr > 4) nr = 4;
    int maxb = -1;  // uniform across block: all threads read same map entries
    for (int r = 0; r < nr; ++r) maxb = max(maxb, map[nodeof[base + r]] & 3);
    if (maxb < kk) continue;  // no row of this tile is in S_kk (uniform branch)
    for (int idx = tid; idx < nr * 64; idx += NT) {
      int r = idx >> 6, qq = idx & 63;
      float4 hv = hin4[(size_t)(base + r) * 64 + qq];
      hv.x = fmaxf(hv.x, 0.f); hv.y = fmaxf(hv.y, 0.f);
      hv.z = fmaxf(hv.z, 0.f); hv.w = fmaxf(hv.w, 0.f);
      *(float4*)&hs[r][qq * 4] = hv;
    }
    __syncthreads();
    float4 a0 = {0,0,0,0}, a1 = a0, a2 = a0, a3 = a0;
#pragma unroll 4
    for (int m = kg * 64; m < kg * 64 + 64; ++m) {
      float4 w = W4[(size_t)m * 64 + q];
      a0 = fma4(hs[0][m], w, a0); a1 = fma4(hs[1][m], w, a1);
      a2 = fma4(hs[2][m], w, a2); a3 = fma4(hs[3][m], w, a3);
    }
    red[0][kg][q] = a0; red[1][kg][q] = a1; red[2][kg][q] = a2; red[3][kg][q] = a3;
    __syncthreads();
    if (tid < 64) {
      float4 bb = bk4[tid];
      for (int r = 0; r < nr; ++r) {
        float4 s = red[r][0][tid], s1 = red[r][1][tid], s2 = red[r][2][tid], s3 = red[r][3][tid];
        s.x += s1.x + s2.x + s3.x; s.y += s1.y + s2.y + s3.y;
        s.z += s1.z + s2.z + s3.z; s.w += s1.w + s2.w + s3.w;
        g4[(size_t)(base + r) * 64 + tid] = s;
        int u = nodeof[base + r];
        int mv = map[u];
        if ((mv & 3) >= kk + 1) {
          float dv = 1.0f / sqrtf(deg[u] + 1.0f);
          float d2 = dv * dv;
          float4 h;
          h.x = bb.x + d2 * s.x; h.y = bb.y + d2 * s.y;
          h.z = bb.z + d2 * s.z; h.w = bb.w + d2 * s.w;
          hout4[(size_t)(base + r) * 64 + tid] = h;
        }
      }
    }
    __syncthreads();
  }
}

// hout[slot(col)] += dinv(row)*ea*dinv(col) * g[slot(row)] over layer-k active edges.
__global__ void k_scat(const int* __restrict__ ei, int E, const int* __restrict__ meta,
                       int ecntIdx, const int* __restrict__ elist,
                       const float* __restrict__ ea, const int* __restrict__ map,
                       const float* __restrict__ deg, const float* __restrict__ g,
                       float* __restrict__ hout) {
  __shared__ int s_st;
  int tid = threadIdx.x;
  int st = detect_stride(ei, E, &s_st, tid);
  int ne = meta[ecntIdx]; if (ne > CAPE) ne = CAPE;
  for (int i = blockIdx.x; i < ne; i += gridDim.x) {
    int e = elist[i];
    int u = ei[(size_t)e * st], v = ei[(size_t)(E + e) * st];
    int mu = map[u], mv = map[v];
    if (mu < 4 || mv < 4) continue;   // overflow guard (flagged at tail)
    float du  = 1.0f / sqrtf(deg[u] + 1.0f);
    float dvv = 1.0f / sqrtf(deg[v] + 1.0f);
    float nrm = du * ea[e] * dvv;
    atomicAdd(&hout[(size_t)((mv >> 2) - 1) * HDIM + tid],
              nrm * g[(size_t)((mu >> 2) - 1) * HDIM + tid]);
  }
}

// Head stage 1 fused with layer-2 scatter+self (el2 has ~6 edges, all col==target):
// h3row = b2 + dinv_t^2*g[0] + sum nrm*g[su]; v1 = relu(h3row @ Wo1 + bo1).
// 8 blocks x 64 cols; redundant h3row per block (trivial).
__global__ void __launch_bounds__(NT) k_heads1(
    const int* __restrict__ ei, int E, const float* __restrict__ ea,
    const int* __restrict__ meta, const int* __restrict__ map,
    const int* __restrict__ nodeof, const int* __restrict__ el2,
    const float* __restrict__ deg, const float* __restrict__ b2,
    const float* __restrict__ g, const float* __restrict__ Wo1,
    const float* __restrict__ bo1, float* __restrict__ v1) {
  __shared__ int s_st;
  __shared__ float h3[256];
  __shared__ float4 red[256];  // [kg][q], 16x16
  int tid = threadIdx.x;
  int st = detect_stride(ei, E, &s_st, tid);
  int t = nodeof[0];
  float dvt = 1.0f / sqrtf(deg[t] + 1.0f);
  float acc = b2[tid] + dvt * dvt * g[tid];  // slot 0 = target
  int ne2 = meta[7]; if (ne2 > CAPE) ne2 = CAPE;
  for (int i = 0; i < ne2; ++i) {
    int e = el2[i];
    int u = ei[(size_t)e * st];
    int mu = map[u];
    if (mu < 4) continue;
    float du = 1.0f / sqrtf(deg[u] + 1.0f);
    acc += du * ea[e] * dvt * g[(size_t)((mu >> 2) - 1) * HDIM + tid];
  }
  h3[tid] = acc;
  __syncthreads();
  // matmul: KIN=256, KOUT=512; QPB=16, KG=16, KQ=16
  int q = tid & 15, kg = tid >> 4;
  const float4* W4 = (const float4*)Wo1;
  int quad = blockIdx.x * 16 + q;
  float4 a = {0,0,0,0};
#pragma unroll
  for (int k = kg * 16; k < kg * 16 + 16; ++k)
    a = fma4(h3[k], W4[(size_t)k * 128 + quad], a);
  red[kg * 16 + q] = a;
  __syncthreads();
  if (tid < 16) {
    float4 s = red[tid];
    for (int g2 = 1; g2 < 16; ++g2) {
      float4 r = red[g2 * 16 + tid];
      s.x += r.x; s.y += r.y; s.z += r.z; s.w += r.w;
    }
    float4 bb = ((const float4*)bo1)[blockIdx.x * 16 + tid];
    s.x = fmaxf(s.x + bb.x, 0.f); s.y = fmaxf(s.y + bb.y, 0.f);
    s.z = fmaxf(s.z + bb.z, 0.f); s.w = fmaxf(s.w + bb.w, 0.f);
    ((float4*)v1)[blockIdx.x * 16 + tid] = s;
  }
}

// Generic head stage, float4: vout = act(vin @ W + b). BLOCKS x (KOUT/BLOCKS) cols.
template <int KIN, int KOUT, int BLOCKS, bool RELU>
__global__ void __launch_bounds__(NT) k_headv(const float* __restrict__ vin,
                                              const float* __restrict__ W,
                                              const float* __restrict__ b,
                                              float* __restrict__ vout) {
  constexpr int QPB = KOUT / (4 * BLOCKS);
  constexpr int KG = 256 / QPB;
  constexpr int KQ = KIN / KG;
  __shared__ float vs[KIN];
  __shared__ float4 red[256];
  int tid = threadIdx.x;
  for (int k = tid; k < KIN; k += NT) vs[k] = vin[k];
  __syncthreads();
  int q = tid % QPB, kg = tid / QPB;
  const float4* W4 = (const float4*)W;
  int quad = blockIdx.x * QPB + q;
  float4 a = {0,0,0,0};
#pragma unroll 8
  for (int k = kg * KQ; k < kg * KQ + KQ; ++k)
    a = fma4(vs[k], W4[(size_t)k * (KOUT / 4) + quad], a);
  red[kg * QPB + q] = a;
  __syncthreads();
  if (tid < QPB) {
    float4 s = red[tid];
    for (int g2 = 1; g2 < KG; ++g2) {
      float4 r = red[g2 * QPB + tid];
      s.x += r.x; s.y += r.y; s.z += r.z; s.w += r.w;
    }
    float4 bb = ((const float4*)b)[blockIdx.x * QPB + tid];
    s.x += bb.x; s.y += bb.y; s.z += bb.z; s.w += bb.w;
    if (RELU) {
      s.x = fmaxf(s.x, 0.f); s.y = fmaxf(s.y, 0.f);
      s.z = fmaxf(s.z, 0.f); s.w = fmaxf(s.w, 0.f);
    }
    ((float4*)vout)[blockIdx.x * QPB + tid] = s;
  }
}

// Tail, float4: v4 = relu(v3 @ Wh2 + bh2) [256->128], out = v4 @ Wh3 + bh3 [128->5].
// Side-channel: capacity overflow -> out[4] = code*1e6.
__global__ void __launch_bounds__(NT) k_tailq(
    const float* __restrict__ vin, const float* __restrict__ Wh2,
    const float* __restrict__ bh2, const float* __restrict__ Wh3,
    const float* __restrict__ bh3, const int* __restrict__ meta,
    float* __restrict__ out) {
  __shared__ float vs[256];
  __shared__ float4 red[256];
  __shared__ float v4s[128];
  int tid = threadIdx.x;
  vs[tid] = vin[tid];
  __syncthreads();
  int q = tid & 31, kg = tid >> 5;  // QPB=32 (128 cols), KG=8, KQ=32
  const float4* W4 = (const float4*)Wh2;
  float4 a = {0,0,0,0};
#pragma unroll 8
  for (int k = kg * 32; k < kg * 32 + 32; ++k)
    a = fma4(vs[k], W4[(size_t)k * 32 + q], a);
  red[kg * 32 + q] = a;
  __syncthreads();
  if (tid < 32) {
    float4 s = red[tid];
    for (int g2 = 1; g2 < 8; ++g2) {
      float4 r = red[g2 * 32 + tid];
      s.x += r.x; s.y += r.y; s.z += r.z; s.w += r.w;
    }
    float4 bb = ((const float4*)bh2)[tid];
    *(float4*)&v4s[tid * 4] = make_float4(fmaxf(s.x + bb.x, 0.f), fmaxf(s.y + bb.y, 0.f),
                                          fmaxf(s.z + bb.z, 0.f), fmaxf(s.w + bb.w, 0.f));
  }
  __syncthreads();
  if (tid < 5) {
    float a2 = bh3[tid];
#pragma unroll 4
    for (int k = 0; k < 128; ++k) a2 = fmaf(v4s[k], Wh3[k * 5 + tid], a2);
    if (tid == 4) {
      int B = 0;
      if (meta[0] > CAPN) B |= 1;
      if (meta[5] > CAPE || meta[6] > CAPE || meta[7] > CAPE) B |= 2;
      if (B) a2 = 1.0e6f * (float)B;
    }
    out[tid] = a2;
  }
}

// Diagnostic: out = [0,0,0,0,D]
__global__ void k_diag(float* __restrict__ out, float D) {
  int tid = threadIdx.x;
  if (tid < 4) out[tid] = 0.0f;
  if (tid == 4) out[tid] = D;
}

extern "C" void kernel_launch(void* const* d_in, const int* in_sizes, int n_in,
                              void* d_out, int out_size, void* d_ws, size_t ws_size,
                              hipStream_t stream) {
  float* out = (float*)d_out;

  // ---- input-mapping tripwire (proven good) ----
  static const long long EXP[18] = {5000000, 600000, 300000, 1, 25600, 256, 196608, 768,
                                    131072, 512, 262144, 512, 131072, 256, 32768, 128, 640, 5};
  if (n_in != 18) {
    k_diag<<<1, 64, 0, stream>>>(out, 3.0e6f + 1000.0f * (float)n_in);
    return;
  }
  for (int i = 0; i < 18; ++i) {
    long long s = in_sizes[i];
    bool ok = (s == EXP[i]) || (i == 1 && s == 2 * EXP[1]);
    if (!ok) {
      k_diag<<<1, 64, 0, stream>>>(out, (float)(i + 1) * 1.0e5f);
      return;
    }
  }

  const float* x   = (const float*)d_in[0];
  const int*   ei  = (const int*)d_in[1];
  const float* ea  = (const float*)d_in[2];
  const int*   tgt = (const int*)d_in[3];
  const float* Wi  = (const float*)d_in[4];
  const float* bi  = (const float*)d_in[5];
  const float* Wg  = (const float*)d_in[6];
  const float* bg  = (const float*)d_in[7];
  const float* Wo1 = (const float*)d_in[8];
  const float* bo1 = (const float*)d_in[9];
  const float* Wo2 = (const float*)d_in[10];
  const float* bo2 = (const float*)d_in[11];
  const float* Wh1 = (const float*)d_in[12];
  const float* bh1 = (const float*)d_in[13];
  const float* Wh2 = (const float*)d_in[14];
  const float* bh2 = (const float*)d_in[15];
  const float* Wh3 = (const float*)d_in[16];
  const float* bh3 = (const float*)d_in[17];

  const int N = 50000, E = 300000;

  // ---- workspace ----
  auto al = [](size_t b) { return (b + 255) & ~(size_t)255; };
  char* ws = (char*)d_ws;
  size_t off = 0;
  auto alloc = [&](size_t bytes) { char* p = ws + off; off += al(bytes); return p; };

  int*   map    = (int*)alloc((size_t)N * 4);
  int*   meta   = (int*)alloc(256);
  float* deg    = (float*)alloc((size_t)N * 4);
  int*   nodeof = (int*)alloc((size_t)CAPN * 4);
  int*   el0    = (int*)alloc((size_t)CAPE * 4);
  int*   el1    = (int*)alloc((size_t)CAPE * 4);
  int*   el2    = (int*)alloc((size_t)CAPE * 4);
  float* g      = (float*)alloc((size_t)CAPN * HDIM * 4);
  float* hA     = (float*)alloc((size_t)CAPN * HDIM * 4);
  float* hB     = (float*)alloc((size_t)CAPN * HDIM * 4);
  float* headv  = (float*)alloc(8192);
  float* v1 = headv;           // 512
  float* v2 = headv + 512;     // 512
  float* v3 = headv + 1024;    // 256

  if (off > ws_size) {
    k_diag<<<1, 64, 0, stream>>>(out, 9.0e6f + (float)(ws_size >> 20));
    return;
  }

  dim3 b256(NT);
  int gE = (E + NT - 1) / NT;

  // 13 dispatches
  k_init<<<256, b256, 0, stream>>>(map, deg, meta, nodeof, tgt, N);
  k_deg_exp3<<<256, b256, 0, stream>>>(ei, ea, E, meta, map, nodeof, el2, deg);
  k_expand<<<gE, b256, 0, stream>>>(ei, E, meta, map, nodeof, el1, 6, 2);
  k_expand<<<gE, b256, 0, stream>>>(ei, E, meta, map, nodeof, el0, 5, 1);

  k_l0q<<<256, b256, 0, stream>>>(meta, map, nodeof, x, Wi, bi, Wg, bg, deg, g, hA);
  k_scat<<<256, b256, 0, stream>>>(ei, E, meta, 5, el0, ea, map, deg, g, hA);

  k_gemv4q<<<256, b256, 0, stream>>>(meta, 1, map, nodeof, hA,
                                     Wg + (size_t)1 * HDIM * HDIM, bg + HDIM, deg, g, hB);
  k_scat<<<256, b256, 0, stream>>>(ei, E, meta, 6, el1, ea, map, deg, g, hB);

  k_gemv4q<<<256, b256, 0, stream>>>(meta, 2, map, nodeof, hB,
                                     Wg + (size_t)2 * HDIM * HDIM, bg + 2 * HDIM, deg, g, hA);
  // layer-2 scatter (+self) fused into head stage 1 (el2 ~6 edges, all -> target)
  k_heads1<<<8, b256, 0, stream>>>(ei, E, ea, meta, map, nodeof, el2, deg,
                                   bg + 2 * HDIM, g, Wo1, bo1, v1);
  k_headv<512, 512, 16, false><<<16, b256, 0, stream>>>(v1, Wo2, bo2, v2);
  k_headv<512, 256, 8, true ><<<8, b256, 0, stream>>>(v2, Wh1, bh1, v3);
  k_tailq<<<1, b256, 0, stream>>>(v3, Wh2, bh2, Wh3, bh3, meta, out);
}

// Round 12
// 82.252 us; speedup vs baseline: 4.9471x; 1.0155x over previous
//
#include <hip/hip_runtime.h>

#define HDIM 256
#define CAPN 4096
#define MAXDEG 64
#define NT 256

// meta: [0]=slot counter, [10]=overflow flags (1=bucket full). map[u]: 0=absent,
// 1=claim-in-progress, else ((slot+1)<<2)|birth (birth 0..3). u in S_l <=>
// map[u]>=4 && (map[u]&3)>=l. Sets nested, slots birth-ordered (descending).
// Per-destination buckets: dcnt[L*CAPN+s], dstl[(L*CAPN+s)*MAXDEG + i] = edge id.

__device__ __forceinline__ float4 fma4(float s, float4 w, float4 a) {
  a.x = fmaf(s, w.x, a.x); a.y = fmaf(s, w.y, a.y);
  a.z = fmaf(s, w.z, a.z); a.w = fmaf(s, w.w, a.w);
  return a;
}

// Per-block edge-index dtype detect: int64 high words (first 64) all zero => stride 2.
__device__ __forceinline__ int detect_stride(const int* __restrict__ ei, int E,
                                             int* s_st, int tid) {
  if (tid < 64) {
    bool nz = (tid < E) && (ei[2 * tid + 1] != 0);
    unsigned long long b = __ballot(nz);
    if (tid == 0) *s_st = (b != 0ULL) ? 1 : 2;
  }
  __syncthreads();
  return *s_st;
}

// Load 4 consecutive cols (e0 multiple of 4, e0+3 < E, E multiple of 4 -> aligned).
__device__ __forceinline__ void load_cols4(const int* __restrict__ ei, int E, int e0,
                                           int st, int c[4]) {
  if (st == 1) {
    int4 v = *(const int4*)&ei[E + e0];
    c[0] = v.x; c[1] = v.y; c[2] = v.z; c[3] = v.w;
  } else {
    int4 v1 = *(const int4*)&ei[(size_t)(E + e0) * 2];
    int4 v2 = *(const int4*)&ei[(size_t)(E + e0) * 2 + 4];
    c[0] = v1.x; c[1] = v1.z; c[2] = v2.x; c[3] = v2.z;
  }
}

// k0: zero map/deg/dcnt (vectorized), seed target (slot 0, birth 3), init meta.
__global__ void k_init(int* __restrict__ map, float* __restrict__ deg,
                       int* __restrict__ meta, int* __restrict__ nodeof,
                       int* __restrict__ dcnt, const int* __restrict__ tgt, int N) {
  int t = tgt[0];
  int gtid = blockIdx.x * blockDim.x + threadIdx.x, gsz = gridDim.x * blockDim.x;
  int4* m4 = (int4*)map;
  float4* d4 = (float4*)deg;
  int nv = N >> 2, tv = t >> 2, tl = t & 3;
  for (int i = gtid; i < nv; i += gsz) {
    int4 z = {0, 0, 0, 0};
    if (i == tv) (&z.x)[tl] = 7;
    m4[i] = z;
    d4[i] = make_float4(0.f, 0.f, 0.f, 0.f);
  }
  for (int i = (nv << 2) + gtid; i < N; i += gsz) { map[i] = (i == t) ? 7 : 0; deg[i] = 0.f; }
  int4* c4 = (int4*)dcnt;
  for (int i = gtid; i < 3 * CAPN / 4; i += gsz) c4[i] = make_int4(0, 0, 0, 0);
  if (gtid == 0) { meta[0] = 1; meta[10] = 0; nodeof[0] = t; }
}

// Qualify + bucket-append + claim for one edge (expansion step l, layer l-1 bucket).
__device__ __forceinline__ void expand_edge(const int* __restrict__ ei, int E, int st,
                                            int e, int mv, int l, int* __restrict__ meta,
                                            int* __restrict__ map, int* __restrict__ nodeof,
                                            int* __restrict__ dcnt, int* __restrict__ dstl) {
  if (mv >= 4 && (mv & 3) >= l) {   // col in S_l (mid-kernel claims birth l-1 excluded)
    int sv = (mv >> 2) - 1;
    int idx = atomicAdd(&dcnt[sv], 1);
    if (idx < MAXDEG) dstl[sv * MAXDEG + idx] = e;
    else atomicOr(&meta[10], 1);
    int r = ei[(size_t)e * st];
    if (atomicCAS(&map[r], 0, 1) == 0) {
      int ns = atomicAdd(&meta[0], 1);
      if (ns < CAPN) { nodeof[ns] = r; map[r] = ((ns + 1) << 2) | (l - 1); }
    }
  }
}

// k1: blocks [0,128): deg[col] += ea over ALL edges; blocks [128,256): expansion l=3.
#define DEGB 128
__global__ void k_deg_exp3(const int* __restrict__ ei, const float* __restrict__ ea,
                           int E, int* __restrict__ meta, int* __restrict__ map,
                           int* __restrict__ nodeof, int* __restrict__ dcnt2,
                           int* __restrict__ dstl2, float* __restrict__ deg) {
  __shared__ int s_st;
  int tid = threadIdx.x;
  int st = detect_stride(ei, E, &s_st, tid);
  if (blockIdx.x < DEGB) {
    int stride = DEGB * NT * 4;
    for (int e0 = (blockIdx.x * NT + tid) * 4; e0 < E; e0 += stride) {
      int ne = E - e0;
      if (ne >= 4) {
        int c[4]; load_cols4(ei, E, e0, st, c);
        float4 w = *(const float4*)&ea[e0];
        atomicAdd(&deg[c[0]], w.x); atomicAdd(&deg[c[1]], w.y);
        atomicAdd(&deg[c[2]], w.z); atomicAdd(&deg[c[3]], w.w);
      } else {
        for (int k = 0; k < ne; ++k)
          atomicAdd(&deg[ei[(size_t)(E + e0 + k) * st]], ea[e0 + k]);
      }
    }
  } else {
    int stride = DEGB * NT * 4;
    for (int e0 = ((blockIdx.x - DEGB) * NT + tid) * 4; e0 < E; e0 += stride) {
      int ne = E - e0;
      if (ne >= 4) {
        int c[4]; load_cols4(ei, E, e0, st, c);
        for (int k = 0; k < 4; ++k)
          expand_edge(ei, E, st, e0 + k, map[c[k]], 3, meta, map, nodeof, dcnt2, dstl2);
      } else {
        for (int k = 0; k < ne; ++k) {
          int c = ei[(size_t)(E + e0 + k) * st];
          expand_edge(ei, E, st, e0 + k, map[c], 3, meta, map, nodeof, dcnt2, dstl2);
        }
      }
    }
  }
}

// Expansion step l (l=2,1): 4 edges/thread, single pass.
__global__ void k_exp4(const int* __restrict__ ei, int E, int* __restrict__ meta,
                       int* __restrict__ map, int* __restrict__ nodeof,
                       int* __restrict__ dcnt, int* __restrict__ dstl, int l) {
  __shared__ int s_st;
  int tid = threadIdx.x;
  int st = detect_stride(ei, E, &s_st, tid);
  int e0 = (blockIdx.x * NT + tid) * 4;
  if (e0 >= E) return;
  int ne = E - e0;
  if (ne >= 4) {
    int c[4]; load_cols4(ei, E, e0, st, c);
    for (int k = 0; k < 4; ++k)
      expand_edge(ei, E, st, e0 + k, map[c[k]], l, meta, map, nodeof, dcnt, dstl);
  } else {
    for (int k = 0; k < ne; ++k) {
      int c = ei[(size_t)(E + e0 + k) * st];
      expand_edge(ei, E, st, e0 + k, map[c], l, meta, map, nodeof, dcnt, dstl);
    }
  }
}

// Layer 0 (proven r11, epilogue removed): per 4 rows: h0 = relu(x@Wi+bi) (LDS),
// g0 = h0 @ W0 -> gout. Thread = (quad q, K-group kg).
__global__ void __launch_bounds__(NT) k_l0q(
    const int* __restrict__ meta, const int* __restrict__ nodeof,
    const float* __restrict__ x, const float* __restrict__ Wi,
    const float* __restrict__ bi, const float* __restrict__ W0,
    float* __restrict__ gout) {
  __shared__ float xs[4][112];
  __shared__ float hs[4][HDIM];
  __shared__ float4 red[4][4][64];
  const float4* Wi4 = (const float4*)Wi;
  const float4* W04 = (const float4*)W0;
  const float4* bi4 = (const float4*)bi;
  float4* g4 = (float4*)gout;
  int ntot = meta[0]; if (ntot > CAPN) ntot = CAPN;
  int tid = threadIdx.x, q = tid & 63, kg = tid >> 6;
  for (int base = blockIdx.x * 4; base < ntot; base += gridDim.x * 4) {
    int nr = ntot - base; if (nr > 4) nr = 4;
    for (int idx = tid; idx < nr * 100; idx += NT) {
      int r = idx / 100, k2 = idx - r * 100;
      xs[r][k2] = x[(size_t)nodeof[base + r] * 100 + k2];
    }
    __syncthreads();
    {
      float4 a0 = {0,0,0,0}, a1 = a0, a2 = a0, a3 = a0;
#pragma unroll 5
      for (int k2 = kg * 25; k2 < kg * 25 + 25; ++k2) {
        float4 w = Wi4[(size_t)k2 * 64 + q];
        a0 = fma4(xs[0][k2], w, a0); a1 = fma4(xs[1][k2], w, a1);
        a2 = fma4(xs[2][k2], w, a2); a3 = fma4(xs[3][k2], w, a3);
      }
      red[0][kg][q] = a0; red[1][kg][q] = a1; red[2][kg][q] = a2; red[3][kg][q] = a3;
    }
    __syncthreads();
    if (tid < 64) {
      float4 bb = bi4[tid];
      for (int r = 0; r < nr; ++r) {
        float4 s = red[r][0][tid], s1 = red[r][1][tid], s2 = red[r][2][tid], s3 = red[r][3][tid];
        s.x = fmaxf(s.x + s1.x + s2.x + s3.x + bb.x, 0.0f);
        s.y = fmaxf(s.y + s1.y + s2.y + s3.y + bb.y, 0.0f);
        s.z = fmaxf(s.z + s1.z + s2.z + s3.z + bb.z, 0.0f);
        s.w = fmaxf(s.w + s1.w + s2.w + s3.w + bb.w, 0.0f);
        *(float4*)&hs[r][tid * 4] = s;
      }
    }
    __syncthreads();
    {
      float4 a0 = {0,0,0,0}, a1 = a0, a2 = a0, a3 = a0;
#pragma unroll 4
      for (int m = kg * 64; m < kg * 64 + 64; ++m) {
        float4 w = W04[(size_t)m * 64 + q];
        a0 = fma4(hs[0][m], w, a0); a1 = fma4(hs[1][m], w, a1);
        a2 = fma4(hs[2][m], w, a2); a3 = fma4(hs[3][m], w, a3);
      }
      red[0][kg][q] = a0; red[1][kg][q] = a1; red[2][kg][q] = a2; red[3][kg][q] = a3;
    }
    __syncthreads();
    if (tid < 64) {
      for (int r = 0; r < nr; ++r) {
        float4 s = red[r][0][tid], s1 = red[r][1][tid], s2 = red[r][2][tid], s3 = red[r][3][tid];
        s.x += s1.x + s2.x + s3.x; s.y += s1.y + s2.y + s3.y;
        s.z += s1.z + s2.z + s3.z; s.w += s1.w + s2.w + s3.w;
        g4[(size_t)(base + r) * 64 + tid] = s;
      }
    }
    __syncthreads();
  }
}

// Layer kk (1,2): gather-aggregate h_kk in LDS from buckets, then g_kk = relu(h)@W.
// h[s] = b + dinv_s^2*gprev[s] + dinv_s * sum_i (dinv_ui*ea_i)*gprev[su_i].
__global__ void __launch_bounds__(NT) k_gv(
    const int* __restrict__ meta, int kk, const int* __restrict__ map,
    const int* __restrict__ nodeof, const int* __restrict__ ei, int E,
    const float* __restrict__ ea, const float* __restrict__ deg,
    const int* __restrict__ dcnt, const int* __restrict__ dstl,
    const float* __restrict__ gprev, const float* __restrict__ W,
    const float* __restrict__ bprev, float* __restrict__ gout) {
  __shared__ int s_st;
  __shared__ float hs[4][HDIM];
  __shared__ float4 red[4][4][64];
  __shared__ int   sul[4][MAXDEG];
  __shared__ float nrml[4][MAXDEG];
  __shared__ float dvr[4];
  __shared__ int   ml[4];
  int tid = threadIdx.x;
  int st = detect_stride(ei, E, &s_st, tid);
  const float4* W4 = (const float4*)W;
  const float4* b4 = (const float4*)bprev;
  const float4* gp4 = (const float4*)gprev;
  float4* go4 = (float4*)gout;
  int ntot = meta[0]; if (ntot > CAPN) ntot = CAPN;
  int q = tid & 63, kg = tid >> 6;
  for (int base = blockIdx.x * 4; base < ntot; base += gridDim.x * 4) {
    int nr = ntot - base; if (nr > 4) nr = 4;
    int maxb = -1;  // uniform: all threads read the same map entries
    for (int r = 0; r < nr; ++r) maxb = max(maxb, map[nodeof[base + r]] & 3);
    if (maxb < kk) continue;  // uniform skip: no row of this tile is in S_kk
    {  // bucket metadata: r = tid>>6, i = tid&63
      int r = tid >> 6, i = tid & 63;
      if (r < nr) {
        int s = base + r;
        int m = dcnt[s]; if (m > MAXDEG) m = MAXDEG;
        if (i == 0) { ml[r] = m; dvr[r] = 1.0f / sqrtf(deg[nodeof[s]] + 1.0f); }
        if (i < m) {
          int e = dstl[s * MAXDEG + i];
          int u = ei[(size_t)e * st];
          int mu = map[u];
          sul[r][i] = (mu >= 4) ? (mu >> 2) - 1 : 0;
          nrml[r][i] = (mu >= 4) ? (1.0f / sqrtf(deg[u] + 1.0f)) * ea[e] : 0.0f;
        }
      }
    }
    __syncthreads();
    for (int idx = tid; idx < nr * 64; idx += NT) {  // h rows (one pass: nr*64<=256)
      int r = idx >> 6, qq = idx & 63;
      int s = base + r;
      float dv = dvr[r], d2 = dv * dv;
      float4 gs = gp4[(size_t)s * 64 + qq];
      float4 acc = b4[qq];
      acc.x = fmaf(d2, gs.x, acc.x); acc.y = fmaf(d2, gs.y, acc.y);
      acc.z = fmaf(d2, gs.z, acc.z); acc.w = fmaf(d2, gs.w, acc.w);
      float4 ms = {0,0,0,0};
      int m = ml[r];
      for (int i = 0; i < m; ++i)
        ms = fma4(nrml[r][i], gp4[(size_t)sul[r][i] * 64 + qq], ms);
      acc.x = fmaxf(fmaf(dv, ms.x, acc.x), 0.0f);
      acc.y = fmaxf(fmaf(dv, ms.y, acc.y), 0.0f);
      acc.z = fmaxf(fmaf(dv, ms.z, acc.z), 0.0f);
      acc.w = fmaxf(fmaf(dv, ms.w, acc.w), 0.0f);
      *(float4*)&hs[r][qq * 4] = acc;
    }
    __syncthreads();
    {  // GEMV: g_out = hs @ W
      float4 a0 = {0,0,0,0}, a1 = a0, a2 = a0, a3 = a0;
#pragma unroll 4
      for (int m = kg * 64; m < kg * 64 + 64; ++m) {
        float4 w = W4[(size_t)m * 64 + q];
        a0 = fma4(hs[0][m], w, a0); a1 = fma4(hs[1][m], w, a1);
        a2 = fma4(hs[2][m], w, a2); a3 = fma4(hs[3][m], w, a3);
      }
      red[0][kg][q] = a0; red[1][kg][q] = a1; red[2][kg][q] = a2; red[3][kg][q] = a3;
    }
    __syncthreads();
    if (tid < 64) {
      for (int r = 0; r < nr; ++r) {
        float4 s = red[r][0][tid], s1 = red[r][1][tid], s2 = red[r][2][tid], s3 = red[r][3][tid];
        s.x += s1.x + s2.x + s3.x; s.y += s1.y + s2.y + s3.y;
        s.z += s1.z + s2.z + s3.z; s.w += s1.w + s2.w + s3.w;
        go4[(size_t)(base + r) * 64 + tid] = s;
      }
    }
    __syncthreads();
  }
}

// Head stage 1 fused with layer-2 aggregation (bucket slot 0 = target):
// h3 = b2 + dvt^2*g2[0] + dvt*sum nrm'*g2[su]; v1 = relu(h3 @ Wo1 + bo1). 8 blocks.
__global__ void __launch_bounds__(NT) k_heads1(
    const int* __restrict__ ei, int E, const float* __restrict__ ea,
    const int* __restrict__ map, const int* __restrict__ nodeof,
    const int* __restrict__ dcnt2, const int* __restrict__ dstl2,
    const float* __restrict__ deg, const float* __restrict__ b2,
    const float* __restrict__ g2, const float* __restrict__ Wo1,
    const float* __restrict__ bo1, float* __restrict__ v1) {
  __shared__ int s_st;
  __shared__ float h3[256];
  __shared__ float4 red[256];
  __shared__ int   sul[MAXDEG];
  __shared__ float nrml[MAXDEG];
  int tid = threadIdx.x;
  int st = detect_stride(ei, E, &s_st, tid);
  int t = nodeof[0];
  float dvt = 1.0f / sqrtf(deg[t] + 1.0f);
  int m = dcnt2[0]; if (m > MAXDEG) m = MAXDEG;
  if (tid < m) {
    int e = dstl2[tid];
    int u = ei[(size_t)e * st];
    int mu = map[u];
    sul[tid] = (mu >= 4) ? (mu >> 2) - 1 : 0;
    nrml[tid] = (mu >= 4) ? (1.0f / sqrtf(deg[u] + 1.0f)) * ea[e] : 0.0f;
  }
  __syncthreads();
  {
    float acc = b2[tid] + dvt * dvt * g2[tid];  // slot 0 = target
    float ms = 0.0f;
    for (int i = 0; i < m; ++i)
      ms = fmaf(nrml[i], g2[(size_t)sul[i] * HDIM + tid], ms);
    h3[tid] = fmaf(dvt, ms, acc);
  }
  __syncthreads();
  int q = tid & 15, kg = tid >> 4;  // KIN=256, KOUT=512: QPB=16, KG=16, KQ=16
  const float4* W4 = (const float4*)Wo1;
  int quad = blockIdx.x * 16 + q;
  float4 a = {0,0,0,0};
#pragma unroll
  for (int k = kg * 16; k < kg * 16 + 16; ++k)
    a = fma4(h3[k], W4[(size_t)k * 128 + quad], a);
  red[kg * 16 + q] = a;
  __syncthreads();
  if (tid < 16) {
    float4 s = red[tid];
    for (int g = 1; g < 16; ++g) {
      float4 r = red[g * 16 + tid];
      s.x += r.x; s.y += r.y; s.z += r.z; s.w += r.w;
    }
    float4 bb = ((const float4*)bo1)[blockIdx.x * 16 + tid];
    s.x = fmaxf(s.x + bb.x, 0.f); s.y = fmaxf(s.y + bb.y, 0.f);
    s.z = fmaxf(s.z + bb.z, 0.f); s.w = fmaxf(s.w + bb.w, 0.f);
    ((float4*)v1)[blockIdx.x * 16 + tid] = s;
  }
}

// Generic head stage, float4 (proven r11): vout = act(vin @ W + b).
template <int KIN, int KOUT, int BLOCKS, bool RELU>
__global__ void __launch_bounds__(NT) k_headv(const float* __restrict__ vin,
                                              const float* __restrict__ W,
                                              const float* __restrict__ b,
                                              float* __restrict__ vout) {
  constexpr int QPB = KOUT / (4 * BLOCKS);
  constexpr int KG = 256 / QPB;
  constexpr int KQ = KIN / KG;
  __shared__ float vs[KIN];
  __shared__ float4 red[256];
  int tid = threadIdx.x;
  for (int k = tid; k < KIN; k += NT) vs[k] = vin[k];
  __syncthreads();
  int q = tid % QPB, kg = tid / QPB;
  const float4* W4 = (const float4*)W;
  int quad = blockIdx.x * QPB + q;
  float4 a = {0,0,0,0};
#pragma unroll 8
  for (int k = kg * KQ; k < kg * KQ + KQ; ++k)
    a = fma4(vs[k], W4[(size_t)k * (KOUT / 4) + quad], a);
  red[kg * QPB + q] = a;
  __syncthreads();
  if (tid < QPB) {
    float4 s = red[tid];
    for (int g = 1; g < KG; ++g) {
      float4 r = red[g * QPB + tid];
      s.x += r.x; s.y += r.y; s.z += r.z; s.w += r.w;
    }
    float4 bb = ((const float4*)b)[blockIdx.x * QPB + tid];
    s.x += bb.x; s.y += bb.y; s.z += bb.z; s.w += bb.w;
    if (RELU) {
      s.x = fmaxf(s.x, 0.f); s.y = fmaxf(s.y, 0.f);
      s.z = fmaxf(s.z, 0.f); s.w = fmaxf(s.w, 0.f);
    }
    ((float4*)vout)[blockIdx.x * QPB + tid] = s;
  }
}

// Tail (proven r11): v4 = relu(v3 @ Wh2 + bh2), out = v4 @ Wh3 + bh3.
// Side-channel: out[4] = code*1e6 on capacity overflow.
__global__ void __launch_bounds__(NT) k_tailq(
    const float* __restrict__ vin, const float* __restrict__ Wh2,
    const float* __restrict__ bh2, const float* __restrict__ Wh3,
    const float* __restrict__ bh3, const int* __restrict__ meta,
    float* __restrict__ out) {
  __shared__ float vs[256];
  __shared__ float4 red[256];
  __shared__ float v4s[128];
  int tid = threadIdx.x;
  vs[tid] = vin[tid];
  __syncthreads();
  int q = tid & 31, kg = tid >> 5;
  const float4* W4 = (const float4*)Wh2;
  float4 a = {0,0,0,0};
#pragma unroll 8
  for (int k = kg * 32; k < kg * 32 + 32; ++k)
    a = fma4(vs[k], W4[(size_t)k * 32 + q], a);
  red[kg * 32 + q] = a;
  __syncthreads();
  if (tid < 32) {
    float4 s = red[tid];
    for (int g = 1; g < 8; ++g) {
      float4 r = red[g * 32 + tid];
      s.x += r.x; s.y += r.y; s.z += r.z; s.w += r.w;
    }
    float4 bb = ((const float4*)bh2)[tid];
    *(float4*)&v4s[tid * 4] = make_float4(fmaxf(s.x + bb.x, 0.f), fmaxf(s.y + bb.y, 0.f),
                                          fmaxf(s.z + bb.z, 0.f), fmaxf(s.w + bb.w, 0.f));
  }
  __syncthreads();
  if (tid < 5) {
    float a2 = bh3[tid];
#pragma unroll 4
    for (int k = 0; k < 128; ++k) a2 = fmaf(v4s[k], Wh3[k * 5 + tid], a2);
    if (tid == 4) {
      int B = 0;
      if (meta[0] > CAPN) B |= 1;
      if (meta[10] != 0) B |= 2;
      if (B) a2 = 1.0e6f * (float)B;
    }
    out[tid] = a2;
  }
}

// Diagnostic: out = [0,0,0,0,D]
__global__ void k_diag(float* __restrict__ out, float D) {
  int tid = threadIdx.x;
  if (tid < 4) out[tid] = 0.0f;
  if (tid == 4) out[tid] = D;
}

extern "C" void kernel_launch(void* const* d_in, const int* in_sizes, int n_in,
                              void* d_out, int out_size, void* d_ws, size_t ws_size,
                              hipStream_t stream) {
  float* out = (float*)d_out;

  // ---- input-mapping tripwire (proven good) ----
  static const long long EXP[18] = {5000000, 600000, 300000, 1, 25600, 256, 196608, 768,
                                    131072, 512, 262144, 512, 131072, 256, 32768, 128, 640, 5};
  if (n_in != 18) {
    k_diag<<<1, 64, 0, stream>>>(out, 3.0e6f + 1000.0f * (float)n_in);
    return;
  }
  for (int i = 0; i < 18; ++i) {
    long long s = in_sizes[i];
    bool ok = (s == EXP[i]) || (i == 1 && s == 2 * EXP[1]);
    if (!ok) {
      k_diag<<<1, 64, 0, stream>>>(out, (float)(i + 1) * 1.0e5f);
      return;
    }
  }

  const float* x   = (const float*)d_in[0];
  const int*   ei  = (const int*)d_in[1];
  const float* ea  = (const float*)d_in[2];
  const int*   tgt = (const int*)d_in[3];
  const float* Wi  = (const float*)d_in[4];
  const float* bi  = (const float*)d_in[5];
  const float* Wg  = (const float*)d_in[6];
  const float* bg  = (const float*)d_in[7];
  const float* Wo1 = (const float*)d_in[8];
  const float* bo1 = (const float*)d_in[9];
  const float* Wo2 = (const float*)d_in[10];
  const float* bo2 = (const float*)d_in[11];
  const float* Wh1 = (const float*)d_in[12];
  const float* bh1 = (const float*)d_in[13];
  const float* Wh2 = (const float*)d_in[14];
  const float* bh2 = (const float*)d_in[15];
  const float* Wh3 = (const float*)d_in[16];
  const float* bh3 = (const float*)d_in[17];

  const int N = 50000, E = 300000;

  // ---- workspace ----
  auto al = [](size_t b) { return (b + 255) & ~(size_t)255; };
  char* ws = (char*)d_ws;
  size_t off = 0;
  auto alloc = [&](size_t bytes) { char* p = ws + off; off += al(bytes); return p; };

  int*   map    = (int*)alloc((size_t)N * 4);
  int*   meta   = (int*)alloc(256);
  float* deg    = (float*)alloc((size_t)N * 4);
  int*   nodeof = (int*)alloc((size_t)CAPN * 4);
  int*   dcnt   = (int*)alloc((size_t)3 * CAPN * 4);
  int*   dstl   = (int*)alloc((size_t)3 * CAPN * MAXDEG * 4);
  float* gA     = (float*)alloc((size_t)CAPN * HDIM * 4);
  float* gB     = (float*)alloc((size_t)CAPN * HDIM * 4);
  float* headv  = (float*)alloc(8192);
  float* v1 = headv;
  float* v2 = headv + 512;
  float* v3 = headv + 1024;

  if (off > ws_size) {
    k_diag<<<1, 64, 0, stream>>>(out, 9.0e6f + (float)(ws_size >> 20));
    return;
  }

  int* dcnt0 = dcnt;               int* dstl0 = dstl;
  int* dcnt1 = dcnt + CAPN;        int* dstl1 = dstl + (size_t)CAPN * MAXDEG;
  int* dcnt2 = dcnt + 2 * CAPN;    int* dstl2 = dstl + (size_t)2 * CAPN * MAXDEG;

  dim3 b256(NT);
  int gE4 = (E + NT * 4 - 1) / (NT * 4);

  // 11 dispatches
  k_init<<<128, b256, 0, stream>>>(map, deg, meta, nodeof, dcnt, tgt, N);
  k_deg_exp3<<<256, b256, 0, stream>>>(ei, ea, E, meta, map, nodeof, dcnt2, dstl2, deg);
  k_exp4<<<gE4, b256, 0, stream>>>(ei, E, meta, map, nodeof, dcnt1, dstl1, 2);
  k_exp4<<<gE4, b256, 0, stream>>>(ei, E, meta, map, nodeof, dcnt0, dstl0, 1);

  k_l0q<<<128, b256, 0, stream>>>(meta, nodeof, x, Wi, bi, Wg, gA);
  k_gv<<<64, b256, 0, stream>>>(meta, 1, map, nodeof, ei, E, ea, deg, dcnt0, dstl0,
                                gA, Wg + (size_t)1 * HDIM * HDIM, bg, gB);
  k_gv<<<64, b256, 0, stream>>>(meta, 2, map, nodeof, ei, E, ea, deg, dcnt1, dstl1,
                                gB, Wg + (size_t)2 * HDIM * HDIM, bg + HDIM, gA);

  k_heads1<<<8, b256, 0, stream>>>(ei, E, ea, map, nodeof, dcnt2, dstl2, deg,
                                   bg + 2 * HDIM, gA, Wo1, bo1, v1);
  k_headv<512, 512, 16, false><<<16, b256, 0, stream>>>(v1, Wo2, bo2, v2);
  k_headv<512, 256, 8, true ><<<8, b256, 0, stream>>>(v2, Wh1, bh1, v3);
  k_tailq<<<1, b256, 0, stream>>>(v3, Wh2, bh2, Wh3, bh3, meta, out);
}